// Round 6
// baseline (279.375 us; speedup 1.0000x reference)
//
#include <hip/hip_runtime.h>
#include <hip/hip_bf16.h>
#include <cstdint>
#include <cstddef>

#define HIDN   512
#define NHEADS 8
#define BATCH  8
#define SLEN   4096
#define TLEN   512
#define SSPLIT 4
#define SCHUNK (SLEN / SSPLIT)          // 1024 s per block
#define SCL2   0.18033688f              // 0.125 * log2(e)

typedef __attribute__((ext_vector_type(8))) short   bf16x8;
typedef __attribute__((ext_vector_type(4))) float   f32x4;
typedef unsigned short u16;
typedef unsigned int   u32;

__device__ __forceinline__ u32 pkbf(float a, float b) {        // accurate RNE
    __hip_bfloat162 h = __float22bfloat162_rn(float2{a, b});
    union { __hip_bfloat162 h; u32 u; } un; un.h = h; return un.u;   // a low
}
// single-instruction pack: v_cvt_pk_bf16_f32 (a -> low16, b -> high16)
__device__ __forceinline__ u32 cvtpk(float a, float b) {
    u32 r;
    asm("v_cvt_pk_bf16_f32 %0, %1, %2" : "=v"(r) : "v"(a), "v"(b));
    return r;
}
// raw v_exp_f32 (2^x): OCML's precise exp2f is ~8-10 instr; this is 1.
__device__ __forceinline__ float fexp2(float x) {
    return __builtin_amdgcn_exp2f(x);
}
__device__ __forceinline__ void gload_lds16(const u16* g, u16* l) {
    __builtin_amdgcn_global_load_lds(
        (const __attribute__((address_space(1))) u32*)g,
        (__attribute__((address_space(3))) u32*)l, 16, 0, 0);
}

// ---------------------------------------------------------------------------
// fp32->bf16 conversion + mask->neg(-1e30) pass.
// float4-unit ranges: X 4194304 | T 524288 | W 262144 | mask 8192 = 4988928
// ---------------------------------------------------------------------------
__global__ __launch_bounds__(256) void cvt_all(
    const float* __restrict__ X, const float* __restrict__ Tg,
    const float* __restrict__ Wq, const float* __restrict__ Wk,
    const float* __restrict__ Wv, const float* __restrict__ Wo,
    const int* __restrict__ mask,
    u16* __restrict__ Xc, u16* __restrict__ Tc, u16* __restrict__ Wc,
    float* __restrict__ negf)
{
    int i4 = blockIdx.x * 256 + threadIdx.x;
    if (i4 >= 4980736) {
        int off = i4 - 4980736;
        int4 mv = ((const int4*)mask)[off];
        float4 nv;
        nv.x = mv.x ? 0.f : -1e30f; nv.y = mv.y ? 0.f : -1e30f;
        nv.z = mv.z ? 0.f : -1e30f; nv.w = mv.w ? 0.f : -1e30f;
        ((float4*)negf)[off] = nv;
        return;
    }
    const float* s; u16* d; long off;
    if (i4 < 4194304)      { s = X;  d = Xc; off = i4; }
    else if (i4 < 4718592) { s = Tg; d = Tc; off = i4 - 4194304; }
    else {
        int wi = i4 - 4718592; int widx = wi >> 16;
        s = (widx == 0) ? Wq : (widx == 1) ? Wk : (widx == 2) ? Wv : Wo;
        d = Wc + widx * 262144; off = wi & 65535;
    }
    float4 v = *(const float4*)(s + off * 4);
    uint2 o; o.x = pkbf(v.x, v.y); o.y = pkbf(v.z, v.w);
    *(uint2*)(d + off * 4) = o;
}

// ---------------------------------------------------------------------------
// Pipelined GEMM core (v6): double-buffered LDS staging via global_load_lds,
// counted s_waitcnt vmcnt(4) (never 0 mid-loop) + raw s_barrier -- next
// k-tile's loads stay in flight across the whole compute(k) phase (was: full
// drain 16x per block).  Granule swizzle g^=(row&3) applied on BOTH the
// global source and the LDS read -> 8-way bank conflict cut to 4-way.
// ---------------------------------------------------------------------------
#define GEMM_PIPE_DECLS                                                      \
    const int xg = (qd ^ (m & 3)) * 8;                                       \
    const int f0 = tid, f1 = tid + 256;                                      \
    const int r0r = f0 >> 2, r0c = ((f0 & 3) ^ (r0r & 3)) * 8;               \
    const int r1r = f1 >> 2, r1c = ((f1 & 3) ^ (r1r & 3)) * 8;               \
    const int r0b = (f0 & ~63) * 8, r1b = (f1 & ~63) * 8

#define GSTAGE(Aptr, Bptr, k0, bb) do {                                      \
        gload_lds16(Aptr + (size_t)(m0 + r0r) * HIDN + (k0) + r0c,           \
                    &As[bb][0] + r0b);                                       \
        gload_lds16(Bptr + (size_t)(n0 + r0r) * HIDN + (k0) + r0c,           \
                    &Bs[bb][0] + r0b);                                       \
        gload_lds16(Aptr + (size_t)(m0 + r1r) * HIDN + (k0) + r1c,           \
                    &As[bb][0] + r1b);                                       \
        gload_lds16(Bptr + (size_t)(n0 + r1r) * HIDN + (k0) + r1c,           \
                    &Bs[bb][0] + r1b);                                       \
    } while (0)

#define GCOMP(bb) do {                                                       \
        bf16x8 af[4], bf[4];                                                 \
        _Pragma("unroll")                                                    \
        for (int t = 0; t < 4; ++t) {                                        \
            af[t] = *(bf16x8*)&As[bb][(64 * wm + 16 * t + m) * 32 + xg];     \
            bf[t] = *(bf16x8*)&Bs[bb][(64 * wn + 16 * t + m) * 32 + xg];     \
        }                                                                    \
        _Pragma("unroll")                                                    \
        for (int ti = 0; ti < 4; ++ti)                                       \
            _Pragma("unroll")                                                \
            for (int tj = 0; tj < 4; ++tj)                                   \
                acc[ti][tj] = __builtin_amdgcn_mfma_f32_16x16x32_bf16(       \
                    af[ti], bf[tj], acc[ti][tj], 0, 0, 0);                   \
    } while (0)

#define GEMM_PIPE_LOOP(Aptr, Bptr) do {                                      \
        GSTAGE(Aptr, Bptr, 0, 0);                                            \
        _Pragma("unroll 1")                                                  \
        for (int c = 0; c < (HIDN / 32) - 1; ++c) {                          \
            GSTAGE(Aptr, Bptr, (c + 1) * 32, (c + 1) & 1);                   \
            asm volatile("s_waitcnt vmcnt(4)" ::: "memory");                 \
            __builtin_amdgcn_s_barrier();                                    \
            __builtin_amdgcn_sched_barrier(0);                               \
            GCOMP(c & 1);                                                    \
            __builtin_amdgcn_s_barrier();                                    \
            __builtin_amdgcn_sched_barrier(0);                               \
        }                                                                    \
        asm volatile("s_waitcnt vmcnt(0)" ::: "memory");                     \
        __builtin_amdgcn_s_barrier();                                        \
        __builtin_amdgcn_sched_barrier(0);                                   \
        GCOMP(((HIDN / 32) - 1) & 1);                                        \
    } while (0)

// ---------------------------------------------------------------------------
// GEMM A-orientation: Y = A @ W^T + bias, A rows staged as MFMA-A.
// MODE 0: fp32 Y[n*512+o] (out-proj).  MODE 2: bf16 (B,H,dk,seq) = V^T,
// uint2 (4 consecutive seq) stores.
// ---------------------------------------------------------------------------
template<int MODE, int SEQ>
__global__ __launch_bounds__(256)
void gemm_bf16(const u16* __restrict__ A, const u16* __restrict__ Bw,
               const float* __restrict__ bias, void* __restrict__ Yv)
{
    __shared__ u16 As[2][128 * 32];
    __shared__ u16 Bs[2][128 * 32];
    const int tid = threadIdx.x;
    const int lane = tid & 63, w = tid >> 6;
    const int m = lane & 15, qd = lane >> 4;
    const int wm = w >> 1, wn = w & 1;
    const int m0 = blockIdx.y * 128, n0 = blockIdx.x * 128;
    GEMM_PIPE_DECLS;

    f32x4 acc[4][4];
#pragma unroll
    for (int i = 0; i < 4; ++i)
#pragma unroll
        for (int j = 0; j < 4; ++j) acc[i][j] = (f32x4){0.f, 0.f, 0.f, 0.f};

    GEMM_PIPE_LOOP(A, Bw);

#pragma unroll
    for (int ti = 0; ti < 4; ++ti) {
        const int gr0 = m0 + 64 * wm + 16 * ti + 4 * qd;
#pragma unroll
        for (int tj = 0; tj < 4; ++tj) {
            const int gcol = n0 + 64 * wn + 16 * tj + m;
            const float bv = bias[gcol];
            if (MODE == 0) {
                float* Y = (float*)Yv;
#pragma unroll
                for (int i = 0; i < 4; ++i)
                    Y[(size_t)(gr0 + i) * HIDN + gcol] = acc[ti][tj][i] + bv;
            } else {
                u16* Y = (u16*)Yv;
                const int b = gr0 / SEQ, h = gcol >> 6, d = gcol & 63;
                const int r = gr0 & (SEQ - 1);
                uint2 o;
                o.x = pkbf(acc[ti][tj][0] + bv, acc[ti][tj][1] + bv);
                o.y = pkbf(acc[ti][tj][2] + bv, acc[ti][tj][3] + bv);
                *(uint2*)&Y[(((size_t)(b * 8 + h)) * 64 + d) * SEQ + r] = o;
            }
        }
    }
}

// ---------------------------------------------------------------------------
// GEMM W-orientation (for Q,K projections): C[o][sample] = W·X^T + bias.
// C rows = output channel o -> each lane holds 4 consecutive d (head dim)
// -> coalesced uint2 bf16 stores into (B,H,seq,64).
// ---------------------------------------------------------------------------
template<int SEQ>
__global__ __launch_bounds__(256)
void gemm_wxT(const u16* __restrict__ Wm, const u16* __restrict__ X,
              const float* __restrict__ bias, u16* __restrict__ Y)
{
    __shared__ u16 As[2][128 * 32];   // W rows (o)
    __shared__ u16 Bs[2][128 * 32];   // X rows (samples)
    const int tid = threadIdx.x;
    const int lane = tid & 63, w = tid >> 6;
    const int m = lane & 15, qd = lane >> 4;
    const int wm = w >> 1, wn = w & 1;
    const int m0 = blockIdx.y * 128, n0 = blockIdx.x * 128;
    GEMM_PIPE_DECLS;

    f32x4 acc[4][4];
#pragma unroll
    for (int i = 0; i < 4; ++i)
#pragma unroll
        for (int j = 0; j < 4; ++j) acc[i][j] = (f32x4){0.f, 0.f, 0.f, 0.f};

    GEMM_PIPE_LOOP(Wm, X);

#pragma unroll
    for (int ti = 0; ti < 4; ++ti) {
        const int o = m0 + 64 * wm + 16 * ti + 4 * qd;      // 4-aligned
        const float4 bv = *(const float4*)&bias[o];
        const int h = o >> 6, d0 = o & 63;
#pragma unroll
        for (int tj = 0; tj < 4; ++tj) {
            const int n = n0 + 64 * wn + 16 * tj + m;       // sample
            const int b = n / SEQ, r = n & (SEQ - 1);
            uint2 pk;
            pk.x = pkbf(acc[ti][tj][0] + bv.x, acc[ti][tj][1] + bv.y);
            pk.y = pkbf(acc[ti][tj][2] + bv.z, acc[ti][tj][3] + bv.w);
            *(uint2*)&Y[(((size_t)(b * 8 + h)) * SEQ + r) * 64 + d0] = pk;
        }
    }
}

// ---------------------------------------------------------------------------
// Flash attention v5: cooperative LDS staging + counted-vmcnt pipeline +
// raw v_exp_f32 softmax.  (Unchanged this round.)
// Grid (ti=2, si=4, bh=64), 256 thr / 4 waves; wave owns 64 t (4 strips).
// P relayout C->B via per-wave LDS round-trip (XOR-swizzled, no barriers).
// ---------------------------------------------------------------------------
__global__ __launch_bounds__(256, 2)
void attn_part(const u16* __restrict__ Q, const u16* __restrict__ K,
               const u16* __restrict__ Vt, const float* __restrict__ negf,
               float* __restrict__ Opart, float* __restrict__ lpart)
{
    __shared__ char Psh[32768];       // 4 waves x 4 ts x 2KB
    __shared__ u16  KVl[2][8192];     // [buf][ K 4096 u16 | V 4096 u16 ]
    __shared__ float Ngl[1024];       // negf slice for this (b, si)
    const int tid = threadIdx.x;
    const int lane = tid & 63, w = tid >> 6;
    const int m = lane & 15, qd = lane >> 4;
    const int ti = blockIdx.x, si = blockIdx.y, bh = blockIdx.z;
    const int b = bh >> 3;

    const u16* Qp = Q + ((size_t)bh * TLEN + ti * 256) * 64;
    const u16* Kp = K + (size_t)bh * SLEN * 64;
    const u16* Vp = Vt + (size_t)bh * 64 * SLEN;
    const float* np = negf + (size_t)b * SLEN;
    const int s_beg = si * SCHUNK;

    // --- staging decomposition: thread -> (row, swizzled 16B granule) ---
    const int sr = tid >> 3;                      // row 0..31 (half-tile)
    const int sg = ((tid & 7) ^ (sr & 7)) * 8;    // swizzled granule, elems
    const u16* kgb = Kp + (size_t)s_beg * 64 + sr * 64 + sg;
    const u16* vgb = Vp + s_beg + (size_t)sr * SLEN + sg;
    u16* kd = &KVl[0][0]    + tid * 8;
    u16* vd = &KVl[0][4096] + tid * 8;

#define STAGE(cc, bb) do {                                                   \
        const u16* kg_ = kgb + (size_t)(cc) * 4096;                          \
        const u16* vg_ = vgb + (cc) * 64;                                    \
        u16* kd_ = kd + (bb) * 8192;                                         \
        u16* vd_ = vd + (bb) * 8192;                                         \
        gload_lds16(kg_,                     kd_);                           \
        gload_lds16(kg_ + 32 * 64,           kd_ + 2048);                    \
        gload_lds16(vg_,                     vd_);                           \
        gload_lds16(vg_ + (size_t)32 * SLEN, vd_ + 2048);                    \
    } while (0)

    // LDS addresses: row t=m (128B), 8B units XOR-swizzled by m -> conflict-free
    const int wb = w * 8192 + m * 128;
    int waddr[4], ra0[2], ra1[2];
#pragma unroll
    for (int st = 0; st < 4; ++st) waddr[st] = wb + (((4 * st + qd) ^ m) << 3);
#pragma unroll
    for (int ks = 0; ks < 2; ++ks) {
        const int u0 = 8 * ks + 2 * qd;
        ra0[ks] = wb + (((u0) ^ m) << 3);
        ra1[ks] = wb + (((u0 + 1) ^ m) << 3);
    }
    // frag-read swizzled column offsets (u16 units) within K/V LDS tiles
    const int x0 = ((qd    ) ^ (m & 7)) * 8;      // kh/ks = 0
    const int x1 = ((4 + qd) ^ (m & 7)) * 8;      // kh/ks = 1

    bf16x8 qf[4][2];
#pragma unroll
    for (int ts = 0; ts < 4; ++ts)
#pragma unroll
        for (int kh = 0; kh < 2; ++kh)
            qf[ts][kh] = *(const bf16x8*)(Qp + (64 * w + 16 * ts + m) * 64 +
                                          32 * kh + 8 * qd);

    f32x4 O[4][4];
#pragma unroll
    for (int ts = 0; ts < 4; ++ts)
#pragma unroll
        for (int dt = 0; dt < 4; ++dt) O[ts][dt] = (f32x4){0.f, 0.f, 0.f, 0.f};
    float lr[4] = {0.f, 0.f, 0.f, 0.f};

#define CHUNK(cc) do {                                                       \
        const u16* Kl = &KVl[(cc) & 1][0];                                   \
        const u16* Vl = &KVl[(cc) & 1][4096];                                \
        bf16x8 kf[4][2];                                                     \
        _Pragma("unroll")                                                    \
        for (int st = 0; st < 4; ++st) {                                     \
            kf[st][0] = *(const bf16x8*)&Kl[st * 1024 + m * 64 + x0];        \
            kf[st][1] = *(const bf16x8*)&Kl[st * 1024 + m * 64 + x1];        \
        }                                                                    \
        float4 ng[4];                                                        \
        _Pragma("unroll")                                                    \
        for (int st = 0; st < 4; ++st)                                       \
            ng[st] = *(const float4*)&Ngl[((cc) << 6) + (st << 4) + (qd << 2)]; \
        _Pragma("unroll")                                                    \
        for (int ts = 0; ts < 4; ++ts) {                                     \
            f32x4 S[4];                                                      \
            _Pragma("unroll")                                                \
            for (int st = 0; st < 4; ++st) {                                 \
                f32x4 cc2 = (f32x4){0.f, 0.f, 0.f, 0.f};                     \
                cc2 = __builtin_amdgcn_mfma_f32_16x16x32_bf16(               \
                          kf[st][0], qf[ts][0], cc2, 0, 0, 0);               \
                cc2 = __builtin_amdgcn_mfma_f32_16x16x32_bf16(               \
                          kf[st][1], qf[ts][1], cc2, 0, 0, 0);               \
                S[st] = cc2;                                                 \
            }                                                                \
            float ls = 0.f;                                                  \
            _Pragma("unroll")                                                \
            for (int st = 0; st < 4; ++st) {                                 \
                const float p0 = fexp2(fmaf(S[st][0], SCL2, ng[st].x));      \
                const float p1 = fexp2(fmaf(S[st][1], SCL2, ng[st].y));      \
                const float p2 = fexp2(fmaf(S[st][2], SCL2, ng[st].z));      \
                const float p3 = fexp2(fmaf(S[st][3], SCL2, ng[st].w));      \
                ls += (p0 + p1) + (p2 + p3);                                 \
                *(uint2*)&Psh[waddr[st] + ts * 2048] =                       \
                    make_uint2(cvtpk(p0, p1), cvtpk(p2, p3));                \
            }                                                                \
            lr[ts] += ls;                                                    \
        }                                                                    \
        bf16x8 vf[4][2];                                                     \
        _Pragma("unroll")                                                    \
        for (int dt = 0; dt < 4; ++dt) {                                     \
            vf[dt][0] = *(const bf16x8*)&Vl[dt * 1024 + m * 64 + x0];        \
            vf[dt][1] = *(const bf16x8*)&Vl[dt * 1024 + m * 64 + x1];        \
        }                                                                    \
        __builtin_amdgcn_s_setprio(1);                                       \
        _Pragma("unroll")                                                    \
        for (int ts = 0; ts < 4; ++ts) {                                     \
            _Pragma("unroll")                                                \
            for (int ks = 0; ks < 2; ++ks) {                                 \
                const uint2 r0 = *(uint2*)&Psh[ra0[ks] + ts * 2048];         \
                const uint2 r1 = *(uint2*)&Psh[ra1[ks] + ts * 2048];         \
                union { uint4 u; bf16x8 v; } bu;                             \
                bu.u = make_uint4(r0.x, r0.y, r1.x, r1.y);                   \
                O[ts][0] = __builtin_amdgcn_mfma_f32_16x16x32_bf16(          \
                               vf[0][ks], bu.v, O[ts][0], 0, 0, 0);          \
                O[ts][1] = __builtin_amdgcn_mfma_f32_16x16x32_bf16(          \
                               vf[1][ks], bu.v, O[ts][1], 0, 0, 0);          \
                O[ts][2] = __builtin_amdgcn_mfma_f32_16x16x32_bf16(          \
                               vf[2][ks], bu.v, O[ts][2], 0, 0, 0);          \
                O[ts][3] = __builtin_amdgcn_mfma_f32_16x16x32_bf16(          \
                               vf[3][ks], bu.v, O[ts][3], 0, 0, 0);          \
            }                                                                \
        }                                                                    \
        __builtin_amdgcn_s_setprio(0);                                       \
    } while (0)

    // --- pipeline: stage(c+1) in flight across compute(c) ---
    STAGE(0, 0);
    gload_lds16((const u16*)(np + s_beg) + (size_t)tid * 8,
                ((u16*)Ngl) + tid * 8);
#pragma unroll 1
    for (int c = 0; c < (SCHUNK / 64) - 1; ++c) {
        STAGE(c + 1, (c + 1) & 1);
        asm volatile("s_waitcnt vmcnt(4)" ::: "memory");
        __builtin_amdgcn_s_barrier();
        __builtin_amdgcn_sched_barrier(0);
        CHUNK(c);
        __builtin_amdgcn_s_barrier();
        __builtin_amdgcn_sched_barrier(0);
    }
    asm volatile("s_waitcnt vmcnt(0)" ::: "memory");
    __builtin_amdgcn_s_barrier();
    __builtin_amdgcn_sched_barrier(0);
    CHUNK((SCHUNK / 64) - 1);

#undef STAGE
#undef CHUNK

#pragma unroll
    for (int ts = 0; ts < 4; ++ts) {
        float l = lr[ts];
        l += __shfl_xor(l, 16, 64);
        l += __shfl_xor(l, 32, 64);
        const int t = ti * 256 + 64 * w + 16 * ts + m;
        float* Ob = Opart + (((size_t)(si * 64 + bh)) * 512 + t) * 64;
#pragma unroll
        for (int dt = 0; dt < 4; ++dt)
            *(f32x4*)&Ob[16 * dt + 4 * qd] = O[ts][dt];
        if (qd == 0)
            lpart[((size_t)(si * 64 + bh)) * 512 + t] = l;
    }
}

// ---------------------------------------------------------------------------
// Combine split-S partials: ctx(B,T,512) bf16 = (sum O)/(sum l).
// ---------------------------------------------------------------------------
__global__ __launch_bounds__(256)
void attn_combine(const float* __restrict__ Opart, const float* __restrict__ lpart,
                  u16* __restrict__ ctx)
{
    const int gid = blockIdx.x * 256 + threadIdx.x;
    const int d4 = gid & 15, t = (gid >> 4) & 511, bh = gid >> 13;
    const int b = bh >> 3, h = bh & 7;
    float4 o = {0.f, 0.f, 0.f, 0.f}; float l = 0.f;
#pragma unroll
    for (int si = 0; si < SSPLIT; ++si) {
        const size_t base = ((size_t)(si * 64 + bh)) * 512 + t;
        l += lpart[base];
        const float4 v = *(const float4*)(Opart + base * 64 + d4 * 4);
        o.x += v.x; o.y += v.y; o.z += v.z; o.w += v.w;
    }
    const float r = 1.f / l;
    uint2 pk; pk.x = pkbf(o.x * r, o.y * r); pk.y = pkbf(o.z * r, o.w * r);
    *(uint2*)&ctx[((size_t)(b * 512 + t)) * 512 + h * 64 + d4 * 4] = pk;
}

// ---------------------------------------------------------------------------
extern "C" void kernel_launch(void* const* d_in, const int* in_sizes, int n_in,
                              void* d_out, int out_size, void* d_ws, size_t ws_size,
                              hipStream_t stream)
{
    const float* inputs  = (const float*)d_in[0];
    const float* targets = (const float*)d_in[1];
    const int*   mask    = (const int*)d_in[2];
    const float* Wq = (const float*)d_in[3];
    const float* bq = (const float*)d_in[4];
    const float* Wk = (const float*)d_in[5];
    const float* bk = (const float*)d_in[6];
    const float* Wv = (const float*)d_in[7];
    const float* bv = (const float*)d_in[8];
    const float* Wo = (const float*)d_in[9];
    const float* bo = (const float*)d_in[10];

    char* ws = (char*)d_ws;
    u16*   Xc    = (u16*)(ws);                            // 33,554,432 B
    u16*   Tc    = (u16*)(ws + 33554432);                 //  4,194,304
    u16*   Wc    = (u16*)(ws + 37748736);                 //  2,097,152
    float* negf  = (float*)(ws + 39845888);               //    131,072
    u16*   Qws   = (u16*)(ws + 39976960);                 //  4,194,304
    u16*   Kws   = (u16*)(ws + 44171264);                 // 33,554,432
    u16*   Vtws  = (u16*)(ws + 77725696);                 // 33,554,432
    u16*   Cws   = (u16*)(ws + 111280128);                //  4,194,304
    float* Opart = (float*)(ws + 115474432);              // 33,554,432
    float* lpart = (float*)(ws + 149028864);              //    524,288

    cvt_all<<<19488, 256, 0, stream>>>(inputs, targets, Wq, Wk, Wv, Wo, mask,
                                       Xc, Tc, Wc, negf);

    // Q,K: W-orientation (coalesced head-dim stores)
    gemm_wxT<TLEN><<<dim3(32, 4),  256, 0, stream>>>(Wc,          Tc, bq, Qws);
    gemm_wxT<SLEN><<<dim3(256, 4), 256, 0, stream>>>(Wc + 262144, Xc, bk, Kws);
    // V^T: A-orientation MODE 2
    gemm_bf16<2, SLEN><<<dim3(4, 256), 256, 0, stream>>>(Xc, Wc + 524288, bv, Vtws);

    attn_part<<<dim3(2, SSPLIT, 64), 256, 0, stream>>>(Qws, Kws, Vtws, negf,
                                                       Opart, lpart);
    attn_combine<<<2048, 256, 0, stream>>>(Opart, lpart, Cws);

    gemm_bf16<0, TLEN><<<dim3(4, 32), 256, 0, stream>>>(Cws, Wc + 786432, bo,
                                                        (float*)d_out);
}

// Round 7
// 279.025 us; speedup vs baseline: 1.0013x; 1.0013x over previous
//
#include <hip/hip_runtime.h>
#include <hip/hip_bf16.h>
#include <cstdint>
#include <cstddef>

#define HIDN   512
#define NHEADS 8
#define BATCH  8
#define SLEN   4096
#define TLEN   512
#define SSPLIT 4
#define SCHUNK (SLEN / SSPLIT)          // 1024 s per block
#define SCL2   0.18033688f              // 0.125 * log2(e)

typedef __attribute__((ext_vector_type(8))) short   bf16x8;
typedef __attribute__((ext_vector_type(4))) float   f32x4;
typedef unsigned short u16;
typedef unsigned int   u32;

__device__ __forceinline__ u32 pkbf(float a, float b) {        // accurate RNE
    __hip_bfloat162 h = __float22bfloat162_rn(float2{a, b});
    union { __hip_bfloat162 h; u32 u; } un; un.h = h; return un.u;   // a low
}
// single-instruction pack: v_cvt_pk_bf16_f32 (a -> low16, b -> high16)
__device__ __forceinline__ u32 cvtpk(float a, float b) {
    u32 r;
    asm("v_cvt_pk_bf16_f32 %0, %1, %2" : "=v"(r) : "v"(a), "v"(b));
    return r;
}
// raw v_exp_f32 (2^x): OCML's precise exp2f is ~8-10 instr; this is 1.
__device__ __forceinline__ float fexp2(float x) {
    return __builtin_amdgcn_exp2f(x);
}
__device__ __forceinline__ void gload_lds16(const u16* g, u16* l) {
    __builtin_amdgcn_global_load_lds(
        (const __attribute__((address_space(1))) u32*)g,
        (__attribute__((address_space(3))) u32*)l, 16, 0, 0);
}

// ---------------------------------------------------------------------------
// fp32->bf16 conversion + mask->neg(-1e30) pass.
// float4-unit ranges: X 4194304 | T 524288 | W 262144 | mask 8192 = 4988928
// ---------------------------------------------------------------------------
__global__ __launch_bounds__(256) void cvt_all(
    const float* __restrict__ X, const float* __restrict__ Tg,
    const float* __restrict__ Wq, const float* __restrict__ Wk,
    const float* __restrict__ Wv, const float* __restrict__ Wo,
    const int* __restrict__ mask,
    u16* __restrict__ Xc, u16* __restrict__ Tc, u16* __restrict__ Wc,
    float* __restrict__ negf)
{
    int i4 = blockIdx.x * 256 + threadIdx.x;
    if (i4 >= 4980736) {
        int off = i4 - 4980736;
        int4 mv = ((const int4*)mask)[off];
        float4 nv;
        nv.x = mv.x ? 0.f : -1e30f; nv.y = mv.y ? 0.f : -1e30f;
        nv.z = mv.z ? 0.f : -1e30f; nv.w = mv.w ? 0.f : -1e30f;
        ((float4*)negf)[off] = nv;
        return;
    }
    const float* s; u16* d; long off;
    if (i4 < 4194304)      { s = X;  d = Xc; off = i4; }
    else if (i4 < 4718592) { s = Tg; d = Tc; off = i4 - 4194304; }
    else {
        int wi = i4 - 4718592; int widx = wi >> 16;
        s = (widx == 0) ? Wq : (widx == 1) ? Wk : (widx == 2) ? Wv : Wo;
        d = Wc + widx * 262144; off = wi & 65535;
    }
    float4 v = *(const float4*)(s + off * 4);
    uint2 o; o.x = pkbf(v.x, v.y); o.y = pkbf(v.z, v.w);
    *(uint2*)(d + off * 4) = o;
}

// ---------------------------------------------------------------------------
// GEMM A-orientation: Y = A @ W^T + bias, A rows staged as MFMA-A.
// MODE 0: fp32 Y[n*512+o] (out-proj).  MODE 2: bf16 (B,H,dk,seq) = V^T,
// uint2 (4 consecutive seq) stores.   (Reverted to R5 form: v6 pipeline
// measured neutral-to-negative.)
// ---------------------------------------------------------------------------
template<int MODE, int SEQ>
__global__ __launch_bounds__(256)
void gemm_bf16(const u16* __restrict__ A, const u16* __restrict__ Bw,
               const float* __restrict__ bias, void* __restrict__ Yv)
{
    __shared__ u16 As[128 * 32];
    __shared__ u16 Bs[128 * 32];
    const int tid = threadIdx.x;
    const int lane = tid & 63, w = tid >> 6;
    const int m = lane & 15, qd = lane >> 4;
    const int wm = w >> 1, wn = w & 1;
    const int m0 = blockIdx.y * 128, n0 = blockIdx.x * 128;

    f32x4 acc[4][4];
#pragma unroll
    for (int i = 0; i < 4; ++i)
#pragma unroll
        for (int j = 0; j < 4; ++j) acc[i][j] = (f32x4){0.f, 0.f, 0.f, 0.f};

    for (int k0 = 0; k0 < HIDN; k0 += 32) {
#pragma unroll
        for (int r = 0; r < 2; ++r) {
            const int f = tid + r * 256;
            const int row = f >> 2, c8 = (f & 3) * 8;
            const int fb = f & ~63;
            gload_lds16(A  + (size_t)(m0 + row) * HIDN + k0 + c8, As + fb * 8);
            gload_lds16(Bw + (size_t)(n0 + row) * HIDN + k0 + c8, Bs + fb * 8);
        }
        __syncthreads();
        bf16x8 af[4], bf[4];
#pragma unroll
        for (int t = 0; t < 4; ++t) {
            af[t] = *(bf16x8*)&As[(64 * wm + 16 * t + m) * 32 + 8 * qd];
            bf[t] = *(bf16x8*)&Bs[(64 * wn + 16 * t + m) * 32 + 8 * qd];
        }
#pragma unroll
        for (int ti = 0; ti < 4; ++ti)
#pragma unroll
            for (int tj = 0; tj < 4; ++tj)
                acc[ti][tj] = __builtin_amdgcn_mfma_f32_16x16x32_bf16(
                    af[ti], bf[tj], acc[ti][tj], 0, 0, 0);
        __syncthreads();
    }

#pragma unroll
    for (int ti = 0; ti < 4; ++ti) {
        const int gr0 = m0 + 64 * wm + 16 * ti + 4 * qd;
#pragma unroll
        for (int tj = 0; tj < 4; ++tj) {
            const int gcol = n0 + 64 * wn + 16 * tj + m;
            const float bv = bias[gcol];
            if (MODE == 0) {
                float* Y = (float*)Yv;
#pragma unroll
                for (int i = 0; i < 4; ++i)
                    Y[(size_t)(gr0 + i) * HIDN + gcol] = acc[ti][tj][i] + bv;
            } else {
                u16* Y = (u16*)Yv;
                const int b = gr0 / SEQ, h = gcol >> 6, d = gcol & 63;
                const int r = gr0 & (SEQ - 1);
                uint2 o;
                o.x = pkbf(acc[ti][tj][0] + bv, acc[ti][tj][1] + bv);
                o.y = pkbf(acc[ti][tj][2] + bv, acc[ti][tj][3] + bv);
                *(uint2*)&Y[(((size_t)(b * 8 + h)) * 64 + d) * SEQ + r] = o;
            }
        }
    }
}

// ---------------------------------------------------------------------------
// GEMM W-orientation (for Q,K projections): C[o][sample] = W·X^T + bias.
// C rows = output channel o -> each lane holds 4 consecutive d (head dim)
// -> coalesced uint2 bf16 stores into (B,H,seq,64).
// ---------------------------------------------------------------------------
template<int SEQ>
__global__ __launch_bounds__(256)
void gemm_wxT(const u16* __restrict__ Wm, const u16* __restrict__ X,
              const float* __restrict__ bias, u16* __restrict__ Y)
{
    __shared__ u16 As[128 * 32];   // W rows (o)
    __shared__ u16 Bs[128 * 32];   // X rows (samples)
    const int tid = threadIdx.x;
    const int lane = tid & 63, w = tid >> 6;
    const int m = lane & 15, qd = lane >> 4;
    const int wm = w >> 1, wn = w & 1;
    const int m0 = blockIdx.y * 128, n0 = blockIdx.x * 128;

    f32x4 acc[4][4];
#pragma unroll
    for (int i = 0; i < 4; ++i)
#pragma unroll
        for (int j = 0; j < 4; ++j) acc[i][j] = (f32x4){0.f, 0.f, 0.f, 0.f};

    for (int k0 = 0; k0 < HIDN; k0 += 32) {
#pragma unroll
        for (int r = 0; r < 2; ++r) {
            const int f = tid + r * 256;
            const int row = f >> 2, c8 = (f & 3) * 8;
            const int fb = f & ~63;
            gload_lds16(Wm + (size_t)(m0 + row) * HIDN + k0 + c8, As + fb * 8);
            gload_lds16(X  + (size_t)(n0 + row) * HIDN + k0 + c8, Bs + fb * 8);
        }
        __syncthreads();
        bf16x8 af[4], bf[4];
#pragma unroll
        for (int t = 0; t < 4; ++t) {
            af[t] = *(bf16x8*)&As[(64 * wm + 16 * t + m) * 32 + 8 * qd];
            bf[t] = *(bf16x8*)&Bs[(64 * wn + 16 * t + m) * 32 + 8 * qd];
        }
#pragma unroll
        for (int ti = 0; ti < 4; ++ti)
#pragma unroll
            for (int tj = 0; tj < 4; ++tj)
                acc[ti][tj] = __builtin_amdgcn_mfma_f32_16x16x32_bf16(
                    af[ti], bf[tj], acc[ti][tj], 0, 0, 0);
        __syncthreads();
    }

#pragma unroll
    for (int ti = 0; ti < 4; ++ti) {
        const int o = m0 + 64 * wm + 16 * ti + 4 * qd;      // 4-aligned
        const float4 bv = *(const float4*)&bias[o];
        const int h = o >> 6, d0 = o & 63;
#pragma unroll
        for (int tj = 0; tj < 4; ++tj) {
            const int n = n0 + 64 * wn + 16 * tj + m;       // sample
            const int b = n / SEQ, r = n & (SEQ - 1);
            uint2 pk;
            pk.x = pkbf(acc[ti][tj][0] + bv.x, acc[ti][tj][1] + bv.y);
            pk.y = pkbf(acc[ti][tj][2] + bv.z, acc[ti][tj][3] + bv.w);
            *(uint2*)&Y[(((size_t)(b * 8 + h)) * SEQ + r) * 64 + d0] = pk;
        }
    }
}

// ---------------------------------------------------------------------------
// Flash attention v7: occupancy 2->3 blocks/CU.
//   R6 counters: attn_part is the largest kernel (58us), Occupancy 17%,
//   MFMA+VALU ~59% -> ~40% stall is latency with only 2 blocks/CU (grid 512
//   AND 68KB LDS both capped at 2).  Fix: ti split 2->4 (t-tile 128/block)
//   -> grid 1024 (4/CU available), per-wave state halves (qf[2][2],O[2][4]),
//   Psh halves to 16KB -> LDS 52KB -> 3 blocks/CU (159744 <= 163840).
//   Zero extra HBM: the 4 ti-blocks of one (si,bh) share K/V via L2 (dedup
//   already proven at ti=2: FETCH 74MB = one-pass).
// Grid (ti=4, si=4, bh=64), 256 thr / 4 waves; wave owns 32 t (2 strips).
// P relayout C->B via per-wave LDS round-trip (XOR-swizzled, no barriers).
// ---------------------------------------------------------------------------
__global__ __launch_bounds__(256, 3)
void attn_part(const u16* __restrict__ Q, const u16* __restrict__ K,
               const u16* __restrict__ Vt, const float* __restrict__ negf,
               float* __restrict__ Opart, float* __restrict__ lpart)
{
    __shared__ char Psh[16384];       // 4 waves x 2 ts x 2KB
    __shared__ u16  KVl[2][8192];     // [buf][ K 4096 u16 | V 4096 u16 ]
    __shared__ float Ngl[1024];       // negf slice for this (b, si)
    const int tid = threadIdx.x;
    const int lane = tid & 63, w = tid >> 6;
    const int m = lane & 15, qd = lane >> 4;
    const int ti = blockIdx.x, si = blockIdx.y, bh = blockIdx.z;
    const int b = bh >> 3;

    const u16* Qp = Q + ((size_t)bh * TLEN + ti * 128) * 64;
    const u16* Kp = K + (size_t)bh * SLEN * 64;
    const u16* Vp = Vt + (size_t)bh * 64 * SLEN;
    const float* np = negf + (size_t)b * SLEN;
    const int s_beg = si * SCHUNK;

    // --- staging decomposition: thread -> (row, swizzled 16B granule) ---
    const int sr = tid >> 3;                      // row 0..31 (half-tile)
    const int sg = ((tid & 7) ^ (sr & 7)) * 8;    // swizzled granule, elems
    const u16* kgb = Kp + (size_t)s_beg * 64 + sr * 64 + sg;
    const u16* vgb = Vp + s_beg + (size_t)sr * SLEN + sg;
    u16* kd = &KVl[0][0]    + tid * 8;
    u16* vd = &KVl[0][4096] + tid * 8;

#define STAGE(cc, bb) do {                                                   \
        const u16* kg_ = kgb + (size_t)(cc) * 4096;                          \
        const u16* vg_ = vgb + (cc) * 64;                                    \
        u16* kd_ = kd + (bb) * 8192;                                         \
        u16* vd_ = vd + (bb) * 8192;                                         \
        gload_lds16(kg_,                     kd_);                           \
        gload_lds16(kg_ + 32 * 64,           kd_ + 2048);                    \
        gload_lds16(vg_,                     vd_);                           \
        gload_lds16(vg_ + (size_t)32 * SLEN, vd_ + 2048);                    \
    } while (0)

    // LDS addresses: row t=m (128B), 8B units XOR-swizzled by m -> conflict-free
    const int wb = w * 4096 + m * 128;
    int waddr[4], ra0[2], ra1[2];
#pragma unroll
    for (int st = 0; st < 4; ++st) waddr[st] = wb + (((4 * st + qd) ^ m) << 3);
#pragma unroll
    for (int ks = 0; ks < 2; ++ks) {
        const int u0 = 8 * ks + 2 * qd;
        ra0[ks] = wb + (((u0) ^ m) << 3);
        ra1[ks] = wb + (((u0 + 1) ^ m) << 3);
    }
    // frag-read swizzled column offsets (u16 units) within K/V LDS tiles
    const int x0 = ((qd    ) ^ (m & 7)) * 8;      // kh/ks = 0
    const int x1 = ((4 + qd) ^ (m & 7)) * 8;      // kh/ks = 1

    bf16x8 qf[2][2];
#pragma unroll
    for (int ts = 0; ts < 2; ++ts)
#pragma unroll
        for (int kh = 0; kh < 2; ++kh)
            qf[ts][kh] = *(const bf16x8*)(Qp + (32 * w + 16 * ts + m) * 64 +
                                          32 * kh + 8 * qd);

    f32x4 O[2][4];
#pragma unroll
    for (int ts = 0; ts < 2; ++ts)
#pragma unroll
        for (int dt = 0; dt < 4; ++dt) O[ts][dt] = (f32x4){0.f, 0.f, 0.f, 0.f};
    float lr[2] = {0.f, 0.f};

#define CHUNK(cc) do {                                                       \
        const u16* Kl = &KVl[(cc) & 1][0];                                   \
        const u16* Vl = &KVl[(cc) & 1][4096];                                \
        bf16x8 kf[4][2];                                                     \
        _Pragma("unroll")                                                    \
        for (int st = 0; st < 4; ++st) {                                     \
            kf[st][0] = *(const bf16x8*)&Kl[st * 1024 + m * 64 + x0];        \
            kf[st][1] = *(const bf16x8*)&Kl[st * 1024 + m * 64 + x1];        \
        }                                                                    \
        float4 ng[4];                                                        \
        _Pragma("unroll")                                                    \
        for (int st = 0; st < 4; ++st)                                       \
            ng[st] = *(const float4*)&Ngl[((cc) << 6) + (st << 4) + (qd << 2)]; \
        _Pragma("unroll")                                                    \
        for (int ts = 0; ts < 2; ++ts) {                                     \
            f32x4 S[4];                                                      \
            _Pragma("unroll")                                                \
            for (int st = 0; st < 4; ++st) {                                 \
                f32x4 cc2 = (f32x4){0.f, 0.f, 0.f, 0.f};                     \
                cc2 = __builtin_amdgcn_mfma_f32_16x16x32_bf16(               \
                          kf[st][0], qf[ts][0], cc2, 0, 0, 0);               \
                cc2 = __builtin_amdgcn_mfma_f32_16x16x32_bf16(               \
                          kf[st][1], qf[ts][1], cc2, 0, 0, 0);               \
                S[st] = cc2;                                                 \
            }                                                                \
            float ls = 0.f;                                                  \
            _Pragma("unroll")                                                \
            for (int st = 0; st < 4; ++st) {                                 \
                const float p0 = fexp2(fmaf(S[st][0], SCL2, ng[st].x));      \
                const float p1 = fexp2(fmaf(S[st][1], SCL2, ng[st].y));      \
                const float p2 = fexp2(fmaf(S[st][2], SCL2, ng[st].z));      \
                const float p3 = fexp2(fmaf(S[st][3], SCL2, ng[st].w));      \
                ls += (p0 + p1) + (p2 + p3);                                 \
                *(uint2*)&Psh[waddr[st] + ts * 2048] =                       \
                    make_uint2(cvtpk(p0, p1), cvtpk(p2, p3));                \
            }                                                                \
            lr[ts] += ls;                                                    \
        }                                                                    \
        bf16x8 vf[4][2];                                                     \
        _Pragma("unroll")                                                    \
        for (int dt = 0; dt < 4; ++dt) {                                     \
            vf[dt][0] = *(const bf16x8*)&Vl[dt * 1024 + m * 64 + x0];        \
            vf[dt][1] = *(const bf16x8*)&Vl[dt * 1024 + m * 64 + x1];        \
        }                                                                    \
        __builtin_amdgcn_s_setprio(1);                                       \
        _Pragma("unroll")                                                    \
        for (int ts = 0; ts < 2; ++ts) {                                     \
            _Pragma("unroll")                                                \
            for (int ks = 0; ks < 2; ++ks) {                                 \
                const uint2 r0 = *(uint2*)&Psh[ra0[ks] + ts * 2048];         \
                const uint2 r1 = *(uint2*)&Psh[ra1[ks] + ts * 2048];         \
                union { uint4 u; bf16x8 v; } bu;                             \
                bu.u = make_uint4(r0.x, r0.y, r1.x, r1.y);                   \
                O[ts][0] = __builtin_amdgcn_mfma_f32_16x16x32_bf16(          \
                               vf[0][ks], bu.v, O[ts][0], 0, 0, 0);          \
                O[ts][1] = __builtin_amdgcn_mfma_f32_16x16x32_bf16(          \
                               vf[1][ks], bu.v, O[ts][1], 0, 0, 0);          \
                O[ts][2] = __builtin_amdgcn_mfma_f32_16x16x32_bf16(          \
                               vf[2][ks], bu.v, O[ts][2], 0, 0, 0);          \
                O[ts][3] = __builtin_amdgcn_mfma_f32_16x16x32_bf16(          \
                               vf[3][ks], bu.v, O[ts][3], 0, 0, 0);          \
            }                                                                \
        }                                                                    \
        __builtin_amdgcn_s_setprio(0);                                       \
    } while (0)

    // --- pipeline: stage(c+1) in flight across compute(c) ---
    STAGE(0, 0);
    gload_lds16((const u16*)(np + s_beg) + (size_t)tid * 8,
                ((u16*)Ngl) + tid * 8);
#pragma unroll 1
    for (int c = 0; c < (SCHUNK / 64) - 1; ++c) {
        STAGE(c + 1, (c + 1) & 1);
        asm volatile("s_waitcnt vmcnt(4)" ::: "memory");
        __builtin_amdgcn_s_barrier();
        __builtin_amdgcn_sched_barrier(0);
        CHUNK(c);
        __builtin_amdgcn_s_barrier();
        __builtin_amdgcn_sched_barrier(0);
    }
    asm volatile("s_waitcnt vmcnt(0)" ::: "memory");
    __builtin_amdgcn_s_barrier();
    __builtin_amdgcn_sched_barrier(0);
    CHUNK((SCHUNK / 64) - 1);

#undef STAGE
#undef CHUNK

#pragma unroll
    for (int ts = 0; ts < 2; ++ts) {
        float l = lr[ts];
        l += __shfl_xor(l, 16, 64);
        l += __shfl_xor(l, 32, 64);
        const int t = ti * 128 + 32 * w + 16 * ts + m;
        float* Ob = Opart + (((size_t)(si * 64 + bh)) * 512 + t) * 64;
#pragma unroll
        for (int dt = 0; dt < 4; ++dt)
            *(f32x4*)&Ob[16 * dt + 4 * qd] = O[ts][dt];
        if (qd == 0)
            lpart[((size_t)(si * 64 + bh)) * 512 + t] = l;
    }
}

// ---------------------------------------------------------------------------
// Combine split-S partials: ctx(B,T,512) bf16 = (sum O)/(sum l).
// ---------------------------------------------------------------------------
__global__ __launch_bounds__(256)
void attn_combine(const float* __restrict__ Opart, const float* __restrict__ lpart,
                  u16* __restrict__ ctx)
{
    const int gid = blockIdx.x * 256 + threadIdx.x;
    const int d4 = gid & 15, t = (gid >> 4) & 511, bh = gid >> 13;
    const int b = bh >> 3, h = bh & 7;
    float4 o = {0.f, 0.f, 0.f, 0.f}; float l = 0.f;
#pragma unroll
    for (int si = 0; si < SSPLIT; ++si) {
        const size_t base = ((size_t)(si * 64 + bh)) * 512 + t;
        l += lpart[base];
        const float4 v = *(const float4*)(Opart + base * 64 + d4 * 4);
        o.x += v.x; o.y += v.y; o.z += v.z; o.w += v.w;
    }
    const float r = 1.f / l;
    uint2 pk; pk.x = pkbf(o.x * r, o.y * r); pk.y = pkbf(o.z * r, o.w * r);
    *(uint2*)&ctx[((size_t)(b * 512 + t)) * 512 + h * 64 + d4 * 4] = pk;
}

// ---------------------------------------------------------------------------
extern "C" void kernel_launch(void* const* d_in, const int* in_sizes, int n_in,
                              void* d_out, int out_size, void* d_ws, size_t ws_size,
                              hipStream_t stream)
{
    const float* inputs  = (const float*)d_in[0];
    const float* targets = (const float*)d_in[1];
    const int*   mask    = (const int*)d_in[2];
    const float* Wq = (const float*)d_in[3];
    const float* bq = (const float*)d_in[4];
    const float* Wk = (const float*)d_in[5];
    const float* bk = (const float*)d_in[6];
    const float* Wv = (const float*)d_in[7];
    const float* bv = (const float*)d_in[8];
    const float* Wo = (const float*)d_in[9];
    const float* bo = (const float*)d_in[10];

    char* ws = (char*)d_ws;
    u16*   Xc    = (u16*)(ws);                            // 33,554,432 B
    u16*   Tc    = (u16*)(ws + 33554432);                 //  4,194,304
    u16*   Wc    = (u16*)(ws + 37748736);                 //  2,097,152
    float* negf  = (float*)(ws + 39845888);               //    131,072
    u16*   Qws   = (u16*)(ws + 39976960);                 //  4,194,304
    u16*   Kws   = (u16*)(ws + 44171264);                 // 33,554,432
    u16*   Vtws  = (u16*)(ws + 77725696);                 // 33,554,432
    u16*   Cws   = (u16*)(ws + 111280128);                //  4,194,304
    float* Opart = (float*)(ws + 115474432);              // 33,554,432
    float* lpart = (float*)(ws + 149028864);              //    524,288

    cvt_all<<<19488, 256, 0, stream>>>(inputs, targets, Wq, Wk, Wv, Wo, mask,
                                       Xc, Tc, Wc, negf);

    // Q,K: W-orientation (coalesced head-dim stores)
    gemm_wxT<TLEN><<<dim3(32, 4),  256, 0, stream>>>(Wc,          Tc, bq, Qws);
    gemm_wxT<SLEN><<<dim3(256, 4), 256, 0, stream>>>(Wc + 262144, Xc, bk, Kws);
    // V^T: A-orientation MODE 2
    gemm_bf16<2, SLEN><<<dim3(4, 256), 256, 0, stream>>>(Xc, Wc + 524288, bv, Vtws);

    attn_part<<<dim3(4, SSPLIT, 64), 256, 0, stream>>>(Qws, Kws, Vtws, negf,
                                                       Opart, lpart);
    attn_combine<<<2048, 256, 0, stream>>>(Opart, lpart, Cws);

    gemm_bf16<0, TLEN><<<dim3(4, 32), 256, 0, stream>>>(Cws, Wc + 786432, bo,
                                                        (float*)d_out);
}

// Round 8
// 258.941 us; speedup vs baseline: 1.0789x; 1.0776x over previous
//
#include <hip/hip_runtime.h>
#include <hip/hip_bf16.h>
#include <cstdint>
#include <cstddef>

#define HIDN   512
#define NHEADS 8
#define BATCH  8
#define SLEN   4096
#define TLEN   512
#define SSPLIT 4
#define SCHUNK (SLEN / SSPLIT)          // 1024 s per block
#define SCL2   0.18033688f              // 0.125 * log2(e)

typedef __attribute__((ext_vector_type(8))) short   bf16x8;
typedef __attribute__((ext_vector_type(4))) float   f32x4;
typedef unsigned short u16;
typedef unsigned int   u32;

__device__ __forceinline__ u32 pkbf(float a, float b) {        // accurate RNE
    __hip_bfloat162 h = __float22bfloat162_rn(float2{a, b});
    union { __hip_bfloat162 h; u32 u; } un; un.h = h; return un.u;   // a low
}
// single-instruction pack: v_cvt_pk_bf16_f32 (a -> low16, b -> high16)
__device__ __forceinline__ u32 cvtpk(float a, float b) {
    u32 r;
    asm("v_cvt_pk_bf16_f32 %0, %1, %2" : "=v"(r) : "v"(a), "v"(b));
    return r;
}
// raw v_exp_f32 (2^x): OCML's precise exp2f is ~8-10 instr; this is 1.
__device__ __forceinline__ float fexp2(float x) {
    return __builtin_amdgcn_exp2f(x);
}
__device__ __forceinline__ void gload_lds16(const u16* g, u16* l) {
    __builtin_amdgcn_global_load_lds(
        (const __attribute__((address_space(1))) u32*)g,
        (__attribute__((address_space(3))) u32*)l, 16, 0, 0);
}

// ---------------------------------------------------------------------------
// fp32->bf16 conversion + mask->neg(-1e30) pass.
// float4-unit ranges: X 4194304 | T 524288 | W 262144 | mask 8192 = 4988928
// ---------------------------------------------------------------------------
__global__ __launch_bounds__(256) void cvt_all(
    const float* __restrict__ X, const float* __restrict__ Tg,
    const float* __restrict__ Wq, const float* __restrict__ Wk,
    const float* __restrict__ Wv, const float* __restrict__ Wo,
    const int* __restrict__ mask,
    u16* __restrict__ Xc, u16* __restrict__ Tc, u16* __restrict__ Wc,
    float* __restrict__ negf)
{
    int i4 = blockIdx.x * 256 + threadIdx.x;
    if (i4 >= 4980736) {
        int off = i4 - 4980736;
        int4 mv = ((const int4*)mask)[off];
        float4 nv;
        nv.x = mv.x ? 0.f : -1e30f; nv.y = mv.y ? 0.f : -1e30f;
        nv.z = mv.z ? 0.f : -1e30f; nv.w = mv.w ? 0.f : -1e30f;
        ((float4*)negf)[off] = nv;
        return;
    }
    const float* s; u16* d; long off;
    if (i4 < 4194304)      { s = X;  d = Xc; off = i4; }
    else if (i4 < 4718592) { s = Tg; d = Tc; off = i4 - 4194304; }
    else {
        int wi = i4 - 4718592; int widx = wi >> 16;
        s = (widx == 0) ? Wq : (widx == 1) ? Wk : (widx == 2) ? Wv : Wo;
        d = Wc + widx * 262144; off = wi & 65535;
    }
    float4 v = *(const float4*)(s + off * 4);
    uint2 o; o.x = pkbf(v.x, v.y); o.y = pkbf(v.z, v.w);
    *(uint2*)(d + off * 4) = o;
}

// ---------------------------------------------------------------------------
// GEMM tile bodies (R5-form inner loop: gload_lds16 staging + __syncthreads).
// Shared by the fused projection kernel and the out-projection kernel.
// ---------------------------------------------------------------------------

// A-orientation: Y = A @ W^T + bias.  MODE 0: fp32 Y[n*512+o] (out-proj).
// MODE 2: bf16 (B,H,dk,seq) = V^T, uint2 (4 consecutive seq) stores.
template<int MODE, int SEQ>
__device__ __forceinline__ void gemmA_body(
    const u16* __restrict__ A, const u16* __restrict__ Bw,
    const float* __restrict__ bias, void* __restrict__ Yv,
    int m0, int n0, u16* As, u16* Bs)
{
    const int tid = threadIdx.x;
    const int lane = tid & 63;
    const int w = tid >> 6;
    const int m = lane & 15, qd = lane >> 4;
    const int wm = w >> 1, wn = w & 1;

    f32x4 acc[4][4];
#pragma unroll
    for (int i = 0; i < 4; ++i)
#pragma unroll
        for (int j = 0; j < 4; ++j) acc[i][j] = (f32x4){0.f, 0.f, 0.f, 0.f};

    for (int k0 = 0; k0 < HIDN; k0 += 32) {
#pragma unroll
        for (int r = 0; r < 2; ++r) {
            const int f = tid + r * 256;
            const int row = f >> 2, c8 = (f & 3) * 8;
            const int fb = f & ~63;
            gload_lds16(A  + (size_t)(m0 + row) * HIDN + k0 + c8, As + fb * 8);
            gload_lds16(Bw + (size_t)(n0 + row) * HIDN + k0 + c8, Bs + fb * 8);
        }
        __syncthreads();
        bf16x8 af[4], bf[4];
#pragma unroll
        for (int t = 0; t < 4; ++t) {
            af[t] = *(bf16x8*)&As[(64 * wm + 16 * t + m) * 32 + 8 * qd];
            bf[t] = *(bf16x8*)&Bs[(64 * wn + 16 * t + m) * 32 + 8 * qd];
        }
#pragma unroll
        for (int ti = 0; ti < 4; ++ti)
#pragma unroll
            for (int tj = 0; tj < 4; ++tj)
                acc[ti][tj] = __builtin_amdgcn_mfma_f32_16x16x32_bf16(
                    af[ti], bf[tj], acc[ti][tj], 0, 0, 0);
        __syncthreads();
    }

#pragma unroll
    for (int ti = 0; ti < 4; ++ti) {
        const int gr0 = m0 + 64 * wm + 16 * ti + 4 * qd;
#pragma unroll
        for (int tj = 0; tj < 4; ++tj) {
            const int gcol = n0 + 64 * wn + 16 * tj + m;
            const float bv = bias[gcol];
            if (MODE == 0) {
                float* Y = (float*)Yv;
#pragma unroll
                for (int i = 0; i < 4; ++i)
                    Y[(size_t)(gr0 + i) * HIDN + gcol] = acc[ti][tj][i] + bv;
            } else {
                u16* Y = (u16*)Yv;
                const int b = gr0 / SEQ, h = gcol >> 6, d = gcol & 63;
                const int r = gr0 & (SEQ - 1);
                uint2 o;
                o.x = pkbf(acc[ti][tj][0] + bv, acc[ti][tj][1] + bv);
                o.y = pkbf(acc[ti][tj][2] + bv, acc[ti][tj][3] + bv);
                *(uint2*)&Y[(((size_t)(b * 8 + h)) * 64 + d) * SEQ + r] = o;
            }
        }
    }
}

// W-orientation (Q,K projections): C[o][sample] = W·X^T + bias -> coalesced
// uint2 bf16 stores into (B,H,seq,64).
template<int SEQ>
__device__ __forceinline__ void wxT_body(
    const u16* __restrict__ Wm, const u16* __restrict__ X,
    const float* __restrict__ bias, u16* __restrict__ Y,
    int m0, int n0, u16* As, u16* Bs)
{
    const int tid = threadIdx.x;
    const int lane = tid & 63;
    const int w = tid >> 6;
    const int m = lane & 15, qd = lane >> 4;
    const int wm = w >> 1, wn = w & 1;

    f32x4 acc[4][4];
#pragma unroll
    for (int i = 0; i < 4; ++i)
#pragma unroll
        for (int j = 0; j < 4; ++j) acc[i][j] = (f32x4){0.f, 0.f, 0.f, 0.f};

    for (int k0 = 0; k0 < HIDN; k0 += 32) {
#pragma unroll
        for (int r = 0; r < 2; ++r) {
            const int f = tid + r * 256;
            const int row = f >> 2, c8 = (f & 3) * 8;
            const int fb = f & ~63;
            gload_lds16(Wm + (size_t)(m0 + row) * HIDN + k0 + c8, As + fb * 8);
            gload_lds16(X  + (size_t)(n0 + row) * HIDN + k0 + c8, Bs + fb * 8);
        }
        __syncthreads();
        bf16x8 af[4], bf[4];
#pragma unroll
        for (int t = 0; t < 4; ++t) {
            af[t] = *(bf16x8*)&As[(64 * wm + 16 * t + m) * 32 + 8 * qd];
            bf[t] = *(bf16x8*)&Bs[(64 * wn + 16 * t + m) * 32 + 8 * qd];
        }
#pragma unroll
        for (int ti = 0; ti < 4; ++ti)
#pragma unroll
            for (int tj = 0; tj < 4; ++tj)
                acc[ti][tj] = __builtin_amdgcn_mfma_f32_16x16x32_bf16(
                    af[ti], bf[tj], acc[ti][tj], 0, 0, 0);
        __syncthreads();
    }

#pragma unroll
    for (int ti = 0; ti < 4; ++ti) {
        const int o = m0 + 64 * wm + 16 * ti + 4 * qd;      // 4-aligned
        const float4 bv = *(const float4*)&bias[o];
        const int h = o >> 6, d0 = o & 63;
#pragma unroll
        for (int tj = 0; tj < 4; ++tj) {
            const int n = n0 + 64 * wn + 16 * tj + m;       // sample
            const int b = n / SEQ, r = n & (SEQ - 1);
            uint2 pk;
            pk.x = pkbf(acc[ti][tj][0] + bv.x, acc[ti][tj][1] + bv.y);
            pk.y = pkbf(acc[ti][tj][2] + bv.z, acc[ti][tj][3] + bv.w);
            *(uint2*)&Y[(((size_t)(b * 8 + h)) * SEQ + r) * 64 + d0] = pk;
        }
    }
}

// ---------------------------------------------------------------------------
// Fused projections (v8): K-proj + V-proj + Q-proj in ONE launch.
//   R0..R7 ledger: total - attn = 218+-3 us, stable across GEMM rewrites ->
//   non-attn stack dominated by serialization bubbles/tails across 7 launches
//   (Q-proj = 128 blocks = half-GPU).  Fusing removes 2 kernel boundaries and
//   tail-fills Q under K/V retirement; also makes projection cost VISIBLE in
//   top-5 (or bounds it < attn).
//   blocks [0,1024): K-proj (m0=(b>>8)*128 o-tile, n0=(b&255)*128 samples)
//   blocks [1024,2048): V-proj (m0=(b2>>2)*128 samples, n0=(b2&3)*128 o-tile)
//   blocks [2048,2176): Q-proj (m0=(b2>>5)*128, n0=(b2&31)*128)
// ---------------------------------------------------------------------------
__global__ __launch_bounds__(256)
void proj_all(const u16* __restrict__ Wc, const u16* __restrict__ Tc,
              const u16* __restrict__ Xc,
              const float* __restrict__ bq, const float* __restrict__ bk,
              const float* __restrict__ bv,
              u16* __restrict__ Qws, u16* __restrict__ Kws,
              u16* __restrict__ Vtws)
{
    __shared__ u16 As[128 * 32];
    __shared__ u16 Bs[128 * 32];
    const int bid = blockIdx.x;
    if (bid < 1024) {
        wxT_body<SLEN>(Wc + 262144, Xc, bk, Kws,
                       (bid >> 8) * 128, (bid & 255) * 128, As, Bs);
    } else if (bid < 2048) {
        const int b2 = bid - 1024;
        gemmA_body<2, SLEN>(Xc, Wc + 524288, bv, Vtws,
                            (b2 >> 2) * 128, (b2 & 3) * 128, As, Bs);
    } else {
        const int b2 = bid - 2048;
        wxT_body<TLEN>(Wc, Tc, bq, Qws,
                       (b2 >> 5) * 128, (b2 & 31) * 128, As, Bs);
    }
}

// Out-projection: ctx @ Wo^T + bo (fp32 out), unchanged R5 form.
__global__ __launch_bounds__(256)
void gemm_out(const u16* __restrict__ A, const u16* __restrict__ Bw,
              const float* __restrict__ bias, float* __restrict__ Y)
{
    __shared__ u16 As[128 * 32];
    __shared__ u16 Bs[128 * 32];
    gemmA_body<0, TLEN>(A, Bw, bias, Y,
                        blockIdx.y * 128, blockIdx.x * 128, As, Bs);
}

// ---------------------------------------------------------------------------
// Flash attention v5 (reverted R7's ti=4: FETCH 74->135MB broke K/V dedup,
// +6us).  Cooperative LDS staging + counted-vmcnt pipeline + raw v_exp_f32.
// Grid (ti=2, si=4, bh=64), 256 thr / 4 waves; wave owns 64 t (4 strips).
// P relayout C->B via per-wave LDS round-trip (XOR-swizzled, no barriers).
// ---------------------------------------------------------------------------
__global__ __launch_bounds__(256, 2)
void attn_part(const u16* __restrict__ Q, const u16* __restrict__ K,
               const u16* __restrict__ Vt, const float* __restrict__ negf,
               float* __restrict__ Opart, float* __restrict__ lpart)
{
    __shared__ char Psh[32768];       // 4 waves x 4 ts x 2KB
    __shared__ u16  KVl[2][8192];     // [buf][ K 4096 u16 | V 4096 u16 ]
    __shared__ float Ngl[1024];       // negf slice for this (b, si)
    const int tid = threadIdx.x;
    const int lane = tid & 63, w = tid >> 6;
    const int m = lane & 15, qd = lane >> 4;
    const int ti = blockIdx.x, si = blockIdx.y, bh = blockIdx.z;
    const int b = bh >> 3;

    const u16* Qp = Q + ((size_t)bh * TLEN + ti * 256) * 64;
    const u16* Kp = K + (size_t)bh * SLEN * 64;
    const u16* Vp = Vt + (size_t)bh * 64 * SLEN;
    const float* np = negf + (size_t)b * SLEN;
    const int s_beg = si * SCHUNK;

    // --- staging decomposition: thread -> (row, swizzled 16B granule) ---
    const int sr = tid >> 3;                      // row 0..31 (half-tile)
    const int sg = ((tid & 7) ^ (sr & 7)) * 8;    // swizzled granule, elems
    const u16* kgb = Kp + (size_t)s_beg * 64 + sr * 64 + sg;
    const u16* vgb = Vp + s_beg + (size_t)sr * SLEN + sg;
    u16* kd = &KVl[0][0]    + tid * 8;
    u16* vd = &KVl[0][4096] + tid * 8;

#define STAGE(cc, bb) do {                                                   \
        const u16* kg_ = kgb + (size_t)(cc) * 4096;                          \
        const u16* vg_ = vgb + (cc) * 64;                                    \
        u16* kd_ = kd + (bb) * 8192;                                         \
        u16* vd_ = vd + (bb) * 8192;                                         \
        gload_lds16(kg_,                     kd_);                           \
        gload_lds16(kg_ + 32 * 64,           kd_ + 2048);                    \
        gload_lds16(vg_,                     vd_);                           \
        gload_lds16(vg_ + (size_t)32 * SLEN, vd_ + 2048);                    \
    } while (0)

    // LDS addresses: row t=m (128B), 8B units XOR-swizzled by m -> conflict-free
    const int wb = w * 8192 + m * 128;
    int waddr[4], ra0[2], ra1[2];
#pragma unroll
    for (int st = 0; st < 4; ++st) waddr[st] = wb + (((4 * st + qd) ^ m) << 3);
#pragma unroll
    for (int ks = 0; ks < 2; ++ks) {
        const int u0 = 8 * ks + 2 * qd;
        ra0[ks] = wb + (((u0) ^ m) << 3);
        ra1[ks] = wb + (((u0 + 1) ^ m) << 3);
    }
    // frag-read swizzled column offsets (u16 units) within K/V LDS tiles
    const int x0 = ((qd    ) ^ (m & 7)) * 8;      // kh/ks = 0
    const int x1 = ((4 + qd) ^ (m & 7)) * 8;      // kh/ks = 1

    bf16x8 qf[4][2];
#pragma unroll
    for (int ts = 0; ts < 4; ++ts)
#pragma unroll
        for (int kh = 0; kh < 2; ++kh)
            qf[ts][kh] = *(const bf16x8*)(Qp + (64 * w + 16 * ts + m) * 64 +
                                          32 * kh + 8 * qd);

    f32x4 O[4][4];
#pragma unroll
    for (int ts = 0; ts < 4; ++ts)
#pragma unroll
        for (int dt = 0; dt < 4; ++dt) O[ts][dt] = (f32x4){0.f, 0.f, 0.f, 0.f};
    float lr[4] = {0.f, 0.f, 0.f, 0.f};

#define CHUNK(cc) do {                                                       \
        const u16* Kl = &KVl[(cc) & 1][0];                                   \
        const u16* Vl = &KVl[(cc) & 1][4096];                                \
        bf16x8 kf[4][2];                                                     \
        _Pragma("unroll")                                                    \
        for (int st = 0; st < 4; ++st) {                                     \
            kf[st][0] = *(const bf16x8*)&Kl[st * 1024 + m * 64 + x0];        \
            kf[st][1] = *(const bf16x8*)&Kl[st * 1024 + m * 64 + x1];        \
        }                                                                    \
        float4 ng[4];                                                        \
        _Pragma("unroll")                                                    \
        for (int st = 0; st < 4; ++st)                                       \
            ng[st] = *(const float4*)&Ngl[((cc) << 6) + (st << 4) + (qd << 2)]; \
        _Pragma("unroll")                                                    \
        for (int ts = 0; ts < 4; ++ts) {                                     \
            f32x4 S[4];                                                      \
            _Pragma("unroll")                                                \
            for (int st = 0; st < 4; ++st) {                                 \
                f32x4 cc2 = (f32x4){0.f, 0.f, 0.f, 0.f};                     \
                cc2 = __builtin_amdgcn_mfma_f32_16x16x32_bf16(               \
                          kf[st][0], qf[ts][0], cc2, 0, 0, 0);               \
                cc2 = __builtin_amdgcn_mfma_f32_16x16x32_bf16(               \
                          kf[st][1], qf[ts][1], cc2, 0, 0, 0);               \
                S[st] = cc2;                                                 \
            }                                                                \
            float ls = 0.f;                                                  \
            _Pragma("unroll")                                                \
            for (int st = 0; st < 4; ++st) {                                 \
                const float p0 = fexp2(fmaf(S[st][0], SCL2, ng[st].x));      \
                const float p1 = fexp2(fmaf(S[st][1], SCL2, ng[st].y));      \
                const float p2 = fexp2(fmaf(S[st][2], SCL2, ng[st].z));      \
                const float p3 = fexp2(fmaf(S[st][3], SCL2, ng[st].w));      \
                ls += (p0 + p1) + (p2 + p3);                                 \
                *(uint2*)&Psh[waddr[st] + ts * 2048] =                       \
                    make_uint2(cvtpk(p0, p1), cvtpk(p2, p3));                \
            }                                                                \
            lr[ts] += ls;                                                    \
        }                                                                    \
        bf16x8 vf[4][2];                                                     \
        _Pragma("unroll")                                                    \
        for (int dt = 0; dt < 4; ++dt) {                                     \
            vf[dt][0] = *(const bf16x8*)&Vl[dt * 1024 + m * 64 + x0];        \
            vf[dt][1] = *(const bf16x8*)&Vl[dt * 1024 + m * 64 + x1];        \
        }                                                                    \
        __builtin_amdgcn_s_setprio(1);                                       \
        _Pragma("unroll")                                                    \
        for (int ts = 0; ts < 4; ++ts) {                                     \
            _Pragma("unroll")                                                \
            for (int ks = 0; ks < 2; ++ks) {                                 \
                const uint2 r0 = *(uint2*)&Psh[ra0[ks] + ts * 2048];         \
                const uint2 r1 = *(uint2*)&Psh[ra1[ks] + ts * 2048];         \
                union { uint4 u; bf16x8 v; } bu;                             \
                bu.u = make_uint4(r0.x, r0.y, r1.x, r1.y);                   \
                O[ts][0] = __builtin_amdgcn_mfma_f32_16x16x32_bf16(          \
                               vf[0][ks], bu.v, O[ts][0], 0, 0, 0);          \
                O[ts][1] = __builtin_amdgcn_mfma_f32_16x16x32_bf16(          \
                               vf[1][ks], bu.v, O[ts][1], 0, 0, 0);          \
                O[ts][2] = __builtin_amdgcn_mfma_f32_16x16x32_bf16(          \
                               vf[2][ks], bu.v, O[ts][2], 0, 0, 0);          \
                O[ts][3] = __builtin_amdgcn_mfma_f32_16x16x32_bf16(          \
                               vf[3][ks], bu.v, O[ts][3], 0, 0, 0);          \
            }                                                                \
        }                                                                    \
        __builtin_amdgcn_s_setprio(0);                                       \
    } while (0)

    // --- pipeline: stage(c+1) in flight across compute(c) ---
    STAGE(0, 0);
    gload_lds16((const u16*)(np + s_beg) + (size_t)tid * 8,
                ((u16*)Ngl) + tid * 8);
#pragma unroll 1
    for (int c = 0; c < (SCHUNK / 64) - 1; ++c) {
        STAGE(c + 1, (c + 1) & 1);
        asm volatile("s_waitcnt vmcnt(4)" ::: "memory");
        __builtin_amdgcn_s_barrier();
        __builtin_amdgcn_sched_barrier(0);
        CHUNK(c);
        __builtin_amdgcn_s_barrier();
        __builtin_amdgcn_sched_barrier(0);
    }
    asm volatile("s_waitcnt vmcnt(0)" ::: "memory");
    __builtin_amdgcn_s_barrier();
    __builtin_amdgcn_sched_barrier(0);
    CHUNK((SCHUNK / 64) - 1);

#undef STAGE
#undef CHUNK

#pragma unroll
    for (int ts = 0; ts < 4; ++ts) {
        float l = lr[ts];
        l += __shfl_xor(l, 16, 64);
        l += __shfl_xor(l, 32, 64);
        const int t = ti * 256 + 64 * w + 16 * ts + m;
        float* Ob = Opart + (((size_t)(si * 64 + bh)) * 512 + t) * 64;
#pragma unroll
        for (int dt = 0; dt < 4; ++dt)
            *(f32x4*)&Ob[16 * dt + 4 * qd] = O[ts][dt];
        if (qd == 0)
            lpart[((size_t)(si * 64 + bh)) * 512 + t] = l;
    }
}

// ---------------------------------------------------------------------------
// Combine split-S partials: ctx(B,T,512) bf16 = (sum O)/(sum l).
// ---------------------------------------------------------------------------
__global__ __launch_bounds__(256)
void attn_combine(const float* __restrict__ Opart, const float* __restrict__ lpart,
                  u16* __restrict__ ctx)
{
    const int gid = blockIdx.x * 256 + threadIdx.x;
    const int d4 = gid & 15, t = (gid >> 4) & 511, bh = gid >> 13;
    const int b = bh >> 3, h = bh & 7;
    float4 o = {0.f, 0.f, 0.f, 0.f}; float l = 0.f;
#pragma unroll
    for (int si = 0; si < SSPLIT; ++si) {
        const size_t base = ((size_t)(si * 64 + bh)) * 512 + t;
        l += lpart[base];
        const float4 v = *(const float4*)(Opart + base * 64 + d4 * 4);
        o.x += v.x; o.y += v.y; o.z += v.z; o.w += v.w;
    }
    const float r = 1.f / l;
    uint2 pk; pk.x = pkbf(o.x * r, o.y * r); pk.y = pkbf(o.z * r, o.w * r);
    *(uint2*)&ctx[((size_t)(b * 512 + t)) * 512 + h * 64 + d4 * 4] = pk;
}

// ---------------------------------------------------------------------------
extern "C" void kernel_launch(void* const* d_in, const int* in_sizes, int n_in,
                              void* d_out, int out_size, void* d_ws, size_t ws_size,
                              hipStream_t stream)
{
    const float* inputs  = (const float*)d_in[0];
    const float* targets = (const float*)d_in[1];
    const int*   mask    = (const int*)d_in[2];
    const float* Wq = (const float*)d_in[3];
    const float* bq = (const float*)d_in[4];
    const float* Wk = (const float*)d_in[5];
    const float* bk = (const float*)d_in[6];
    const float* Wv = (const float*)d_in[7];
    const float* bv = (const float*)d_in[8];
    const float* Wo = (const float*)d_in[9];
    const float* bo = (const float*)d_in[10];

    char* ws = (char*)d_ws;
    u16*   Xc    = (u16*)(ws);                            // 33,554,432 B
    u16*   Tc    = (u16*)(ws + 33554432);                 //  4,194,304
    u16*   Wc    = (u16*)(ws + 37748736);                 //  2,097,152
    float* negf  = (float*)(ws + 39845888);               //    131,072
    u16*   Qws   = (u16*)(ws + 39976960);                 //  4,194,304
    u16*   Kws   = (u16*)(ws + 44171264);                 // 33,554,432
    u16*   Vtws  = (u16*)(ws + 77725696);                 // 33,554,432
    u16*   Cws   = (u16*)(ws + 111280128);                //  4,194,304
    float* Opart = (float*)(ws + 115474432);              // 33,554,432
    float* lpart = (float*)(ws + 149028864);              //    524,288

    cvt_all<<<19488, 256, 0, stream>>>(inputs, targets, Wq, Wk, Wv, Wo, mask,
                                       Xc, Tc, Wc, negf);

    // Fused Q+K+V projections (one launch, 2176 blocks)
    proj_all<<<2176, 256, 0, stream>>>(Wc, Tc, Xc, bq, bk, bv,
                                       Qws, Kws, Vtws);

    attn_part<<<dim3(2, SSPLIT, 64), 256, 0, stream>>>(Qws, Kws, Vtws, negf,
                                                       Opart, lpart);
    attn_combine<<<2048, 256, 0, stream>>>(Opart, lpart, Cws);

    gemm_out<<<dim3(4, 32), 256, 0, stream>>>(Cws, Wc + 786432, bo,
                                              (float*)d_out);
}

// Round 9
// 258.647 us; speedup vs baseline: 1.0801x; 1.0011x over previous
//
#include <hip/hip_runtime.h>
#include <hip/hip_bf16.h>
#include <cstdint>
#include <cstddef>

#define HIDN   512
#define NHEADS 8
#define BATCH  8
#define SLEN   4096
#define TLEN   512
#define SSPLIT 4
#define SCHUNK (SLEN / SSPLIT)          // 1024 s per block
#define SCL2   0.18033688f              // 0.125 * log2(e)

typedef __attribute__((ext_vector_type(8))) short   bf16x8;
typedef __attribute__((ext_vector_type(4))) float   f32x4;
typedef unsigned short u16;
typedef unsigned int   u32;

__device__ __forceinline__ u32 pkbf(float a, float b) {        // accurate RNE
    __hip_bfloat162 h = __float22bfloat162_rn(float2{a, b});
    union { __hip_bfloat162 h; u32 u; } un; un.h = h; return un.u;   // a low
}
// single-instruction pack: v_cvt_pk_bf16_f32 (a -> low16, b -> high16)
__device__ __forceinline__ u32 cvtpk(float a, float b) {
    u32 r;
    asm("v_cvt_pk_bf16_f32 %0, %1, %2" : "=v"(r) : "v"(a), "v"(b));
    return r;
}
// raw v_exp_f32 (2^x): OCML's precise exp2f is ~8-10 instr; this is 1.
__device__ __forceinline__ float fexp2(float x) {
    return __builtin_amdgcn_exp2f(x);
}
__device__ __forceinline__ void gload_lds16(const u16* g, u16* l) {
    __builtin_amdgcn_global_load_lds(
        (const __attribute__((address_space(1))) u32*)g,
        (__attribute__((address_space(3))) u32*)l, 16, 0, 0);
}

// ---------------------------------------------------------------------------
// fp32->bf16 conversion + mask->neg(-1e30) pass.
// float4-unit ranges: X 4194304 | T 524288 | W 262144 | mask 8192 = 4988928
// ---------------------------------------------------------------------------
__global__ __launch_bounds__(256) void cvt_all(
    const float* __restrict__ X, const float* __restrict__ Tg,
    const float* __restrict__ Wq, const float* __restrict__ Wk,
    const float* __restrict__ Wv, const float* __restrict__ Wo,
    const int* __restrict__ mask,
    u16* __restrict__ Xc, u16* __restrict__ Tc, u16* __restrict__ Wc,
    float* __restrict__ negf)
{
    int i4 = blockIdx.x * 256 + threadIdx.x;
    if (i4 >= 4980736) {
        int off = i4 - 4980736;
        int4 mv = ((const int4*)mask)[off];
        float4 nv;
        nv.x = mv.x ? 0.f : -1e30f; nv.y = mv.y ? 0.f : -1e30f;
        nv.z = mv.z ? 0.f : -1e30f; nv.w = mv.w ? 0.f : -1e30f;
        ((float4*)negf)[off] = nv;
        return;
    }
    const float* s; u16* d; long off;
    if (i4 < 4194304)      { s = X;  d = Xc; off = i4; }
    else if (i4 < 4718592) { s = Tg; d = Tc; off = i4 - 4194304; }
    else {
        int wi = i4 - 4718592; int widx = wi >> 16;
        s = (widx == 0) ? Wq : (widx == 1) ? Wk : (widx == 2) ? Wv : Wo;
        d = Wc + widx * 262144; off = wi & 65535;
    }
    float4 v = *(const float4*)(s + off * 4);
    uint2 o; o.x = pkbf(v.x, v.y); o.y = pkbf(v.z, v.w);
    *(uint2*)(d + off * 4) = o;
}

// ---------------------------------------------------------------------------
// GEMM tile bodies (v9): 3-deep LDS ring, counted-vmcnt pipeline.
//   R8 counters: proj_all 70us, MfmaUtil 20 / VALUBusy 11 / HBM 33% -> 70%
//   stall = 2-phase stage+drain regime; R6's depth-1 prefetch was null
//   because 16 MFMA (~130cyc) can't cover ~400-900cyc load latency.  Depth-2:
//   stage k(c+2) each iter, vmcnt(8) waits only for stage c (c+1,c+2 stay in
//   flight -> 2 compute phases of cover).  Granule swizzle (source-XOR +
//   read-XOR, verified R6) kills the 4.45M bank-conflict cycles.
//   LDS 3x16KB = 48KB -> 3 blocks/CU.  Fully unrolled: buffer idx static.
// ---------------------------------------------------------------------------

#define GEMM_RING_DECLS                                                      \
    const int xg  = (qd ^ (m & 3)) * 8;                                      \
    const int r0r = tid >> 2,         r0c = ((tid & 3) ^ (r0r & 3)) * 8;     \
    const int r1r = (tid + 256) >> 2, r1c = ((tid & 3) ^ (r1r & 3)) * 8;     \
    const int r0b = (tid & ~63) * 8,  r1b = ((tid + 256) & ~63) * 8

#define PSTG(Aptr, Bptr, bb, k0) do {                                        \
        gload_lds16(Aptr + (size_t)(m0 + r0r) * HIDN + (k0) + r0c,           \
                    &As[bb][0] + r0b);                                       \
        gload_lds16(Bptr + (size_t)(n0 + r0r) * HIDN + (k0) + r0c,           \
                    &Bs[bb][0] + r0b);                                       \
        gload_lds16(Aptr + (size_t)(m0 + r1r) * HIDN + (k0) + r1c,           \
                    &As[bb][0] + r1b);                                       \
        gload_lds16(Bptr + (size_t)(n0 + r1r) * HIDN + (k0) + r1c,           \
                    &Bs[bb][0] + r1b);                                       \
    } while (0)

#define PCMP(bb) do {                                                        \
        bf16x8 af[4], bf[4];                                                 \
        _Pragma("unroll")                                                    \
        for (int t = 0; t < 4; ++t) {                                        \
            af[t] = *(bf16x8*)&As[bb][(64 * wm + 16 * t + m) * 32 + xg];     \
            bf[t] = *(bf16x8*)&Bs[bb][(64 * wn + 16 * t + m) * 32 + xg];     \
        }                                                                    \
        _Pragma("unroll")                                                    \
        for (int ti = 0; ti < 4; ++ti)                                       \
            _Pragma("unroll")                                                \
            for (int tj = 0; tj < 4; ++tj)                                   \
                acc[ti][tj] = __builtin_amdgcn_mfma_f32_16x16x32_bf16(       \
                    af[ti], bf[tj], acc[ti][tj], 0, 0, 0);                   \
    } while (0)

#define WAIT_BAR(N) do {                                                     \
        asm volatile("s_waitcnt vmcnt(" #N ")" ::: "memory");                \
        __builtin_amdgcn_s_barrier();                                        \
        __builtin_amdgcn_sched_barrier(0);                                   \
    } while (0)

#define GEMM_RING_LOOP(Aptr, Bptr) do {                                      \
        PSTG(Aptr, Bptr, 0, 0);                                              \
        PSTG(Aptr, Bptr, 1, 32);                                             \
        _Pragma("unroll")                                                    \
        for (int c = 0; c < 14; ++c) {                                       \
            PSTG(Aptr, Bptr, (c + 2) % 3, (c + 2) * 32);                     \
            WAIT_BAR(8);                                                     \
            PCMP(c % 3);                                                     \
            __builtin_amdgcn_s_barrier();                                    \
            __builtin_amdgcn_sched_barrier(0);                               \
        }                                                                    \
        WAIT_BAR(4);                                                         \
        PCMP(2);                    /* c=14 */                               \
        __builtin_amdgcn_s_barrier();                                        \
        __builtin_amdgcn_sched_barrier(0);                                   \
        WAIT_BAR(0);                                                         \
        PCMP(0);                    /* c=15 */                               \
    } while (0)

// A-orientation: Y = A @ W^T + bias.  MODE 0: fp32 Y[n*512+o] (out-proj).
// MODE 2: bf16 (B,H,dk,seq) = V^T, uint2 (4 consecutive seq) stores.
template<int MODE, int SEQ>
__device__ __forceinline__ void gemmA_body(
    const u16* __restrict__ A, const u16* __restrict__ Bw,
    const float* __restrict__ bias, void* __restrict__ Yv,
    int m0, int n0, u16 (*As)[4096], u16 (*Bs)[4096])
{
    const int tid = threadIdx.x;
    const int lane = tid & 63;
    const int w = tid >> 6;
    const int m = lane & 15, qd = lane >> 4;
    const int wm = w >> 1, wn = w & 1;
    GEMM_RING_DECLS;

    f32x4 acc[4][4];
#pragma unroll
    for (int i = 0; i < 4; ++i)
#pragma unroll
        for (int j = 0; j < 4; ++j) acc[i][j] = (f32x4){0.f, 0.f, 0.f, 0.f};

    GEMM_RING_LOOP(A, Bw);

#pragma unroll
    for (int ti = 0; ti < 4; ++ti) {
        const int gr0 = m0 + 64 * wm + 16 * ti + 4 * qd;
#pragma unroll
        for (int tj = 0; tj < 4; ++tj) {
            const int gcol = n0 + 64 * wn + 16 * tj + m;
            const float bv = bias[gcol];
            if (MODE == 0) {
                float* Y = (float*)Yv;
#pragma unroll
                for (int i = 0; i < 4; ++i)
                    Y[(size_t)(gr0 + i) * HIDN + gcol] = acc[ti][tj][i] + bv;
            } else {
                u16* Y = (u16*)Yv;
                const int b = gr0 / SEQ, h = gcol >> 6, d = gcol & 63;
                const int r = gr0 & (SEQ - 1);
                uint2 o;
                o.x = pkbf(acc[ti][tj][0] + bv, acc[ti][tj][1] + bv);
                o.y = pkbf(acc[ti][tj][2] + bv, acc[ti][tj][3] + bv);
                *(uint2*)&Y[(((size_t)(b * 8 + h)) * 64 + d) * SEQ + r] = o;
            }
        }
    }
}

// W-orientation (Q,K projections): C[o][sample] = W·X^T + bias -> coalesced
// uint2 bf16 stores into (B,H,seq,64).
template<int SEQ>
__device__ __forceinline__ void wxT_body(
    const u16* __restrict__ Wm, const u16* __restrict__ X,
    const float* __restrict__ bias, u16* __restrict__ Y,
    int m0, int n0, u16 (*As)[4096], u16 (*Bs)[4096])
{
    const int tid = threadIdx.x;
    const int lane = tid & 63;
    const int w = tid >> 6;
    const int m = lane & 15, qd = lane >> 4;
    const int wm = w >> 1, wn = w & 1;
    GEMM_RING_DECLS;

    f32x4 acc[4][4];
#pragma unroll
    for (int i = 0; i < 4; ++i)
#pragma unroll
        for (int j = 0; j < 4; ++j) acc[i][j] = (f32x4){0.f, 0.f, 0.f, 0.f};

    GEMM_RING_LOOP(Wm, X);

#pragma unroll
    for (int ti = 0; ti < 4; ++ti) {
        const int o = m0 + 64 * wm + 16 * ti + 4 * qd;      // 4-aligned
        const float4 bv = *(const float4*)&bias[o];
        const int h = o >> 6, d0 = o & 63;
#pragma unroll
        for (int tj = 0; tj < 4; ++tj) {
            const int n = n0 + 64 * wn + 16 * tj + m;       // sample
            const int b = n / SEQ, r = n & (SEQ - 1);
            uint2 pk;
            pk.x = pkbf(acc[ti][tj][0] + bv.x, acc[ti][tj][1] + bv.y);
            pk.y = pkbf(acc[ti][tj][2] + bv.z, acc[ti][tj][3] + bv.w);
            *(uint2*)&Y[(((size_t)(b * 8 + h)) * SEQ + r) * 64 + d0] = pk;
        }
    }
}

// ---------------------------------------------------------------------------
// Fused projections: K-proj + V-proj + Q-proj in ONE launch (R8 win, kept).
//   blocks [0,1024): K-proj | [1024,2048): V-proj | [2048,2176): Q-proj
// ---------------------------------------------------------------------------
__global__ __launch_bounds__(256)
void proj_all(const u16* __restrict__ Wc, const u16* __restrict__ Tc,
              const u16* __restrict__ Xc,
              const float* __restrict__ bq, const float* __restrict__ bk,
              const float* __restrict__ bv,
              u16* __restrict__ Qws, u16* __restrict__ Kws,
              u16* __restrict__ Vtws)
{
    __shared__ u16 As[3][4096];
    __shared__ u16 Bs[3][4096];
    const int bid = blockIdx.x;
    if (bid < 1024) {
        wxT_body<SLEN>(Wc + 262144, Xc, bk, Kws,
                       (bid >> 8) * 128, (bid & 255) * 128, As, Bs);
    } else if (bid < 2048) {
        const int b2 = bid - 1024;
        gemmA_body<2, SLEN>(Xc, Wc + 524288, bv, Vtws,
                            (b2 >> 2) * 128, (b2 & 3) * 128, As, Bs);
    } else {
        const int b2 = bid - 2048;
        wxT_body<TLEN>(Wc, Tc, bq, Qws,
                       (b2 >> 5) * 128, (b2 & 31) * 128, As, Bs);
    }
}

// Out-projection: ctx @ Wo^T + bo (fp32 out), same ring-pipelined body.
__global__ __launch_bounds__(256)
void gemm_out(const u16* __restrict__ A, const u16* __restrict__ Bw,
              const float* __restrict__ bias, float* __restrict__ Y)
{
    __shared__ u16 As[3][4096];
    __shared__ u16 Bs[3][4096];
    gemmA_body<0, TLEN>(A, Bw, bias, Y,
                        blockIdx.y * 128, blockIdx.x * 128, As, Bs);
}

// ---------------------------------------------------------------------------
// Flash attention v5 (unchanged): cooperative LDS staging + counted-vmcnt
// pipeline + raw v_exp_f32.
// Grid (ti=2, si=4, bh=64), 256 thr / 4 waves; wave owns 64 t (4 strips).
// P relayout C->B via per-wave LDS round-trip (XOR-swizzled, no barriers).
// ---------------------------------------------------------------------------
__global__ __launch_bounds__(256, 2)
void attn_part(const u16* __restrict__ Q, const u16* __restrict__ K,
               const u16* __restrict__ Vt, const float* __restrict__ negf,
               float* __restrict__ Opart, float* __restrict__ lpart)
{
    __shared__ char Psh[32768];       // 4 waves x 4 ts x 2KB
    __shared__ u16  KVl[2][8192];     // [buf][ K 4096 u16 | V 4096 u16 ]
    __shared__ float Ngl[1024];       // negf slice for this (b, si)
    const int tid = threadIdx.x;
    const int lane = tid & 63, w = tid >> 6;
    const int m = lane & 15, qd = lane >> 4;
    const int ti = blockIdx.x, si = blockIdx.y, bh = blockIdx.z;
    const int b = bh >> 3;

    const u16* Qp = Q + ((size_t)bh * TLEN + ti * 256) * 64;
    const u16* Kp = K + (size_t)bh * SLEN * 64;
    const u16* Vp = Vt + (size_t)bh * 64 * SLEN;
    const float* np = negf + (size_t)b * SLEN;
    const int s_beg = si * SCHUNK;

    // --- staging decomposition: thread -> (row, swizzled 16B granule) ---
    const int sr = tid >> 3;                      // row 0..31 (half-tile)
    const int sg = ((tid & 7) ^ (sr & 7)) * 8;    // swizzled granule, elems
    const u16* kgb = Kp + (size_t)s_beg * 64 + sr * 64 + sg;
    const u16* vgb = Vp + s_beg + (size_t)sr * SLEN + sg;
    u16* kd = &KVl[0][0]    + tid * 8;
    u16* vd = &KVl[0][4096] + tid * 8;

#define STAGE(cc, bb) do {                                                   \
        const u16* kg_ = kgb + (size_t)(cc) * 4096;                          \
        const u16* vg_ = vgb + (cc) * 64;                                    \
        u16* kd_ = kd + (bb) * 8192;                                         \
        u16* vd_ = vd + (bb) * 8192;                                         \
        gload_lds16(kg_,                     kd_);                           \
        gload_lds16(kg_ + 32 * 64,           kd_ + 2048);                    \
        gload_lds16(vg_,                     vd_);                           \
        gload_lds16(vg_ + (size_t)32 * SLEN, vd_ + 2048);                    \
    } while (0)

    // LDS addresses: row t=m (128B), 8B units XOR-swizzled by m -> conflict-free
    const int wb = w * 8192 + m * 128;
    int waddr[4], ra0[2], ra1[2];
#pragma unroll
    for (int st = 0; st < 4; ++st) waddr[st] = wb + (((4 * st + qd) ^ m) << 3);
#pragma unroll
    for (int ks = 0; ks < 2; ++ks) {
        const int u0 = 8 * ks + 2 * qd;
        ra0[ks] = wb + (((u0) ^ m) << 3);
        ra1[ks] = wb + (((u0 + 1) ^ m) << 3);
    }
    // frag-read swizzled column offsets (u16 units) within K/V LDS tiles
    const int x0 = ((qd    ) ^ (m & 7)) * 8;      // kh/ks = 0
    const int x1 = ((4 + qd) ^ (m & 7)) * 8;      // kh/ks = 1

    bf16x8 qf[4][2];
#pragma unroll
    for (int ts = 0; ts < 4; ++ts)
#pragma unroll
        for (int kh = 0; kh < 2; ++kh)
            qf[ts][kh] = *(const bf16x8*)(Qp + (64 * w + 16 * ts + m) * 64 +
                                          32 * kh + 8 * qd);

    f32x4 O[4][4];
#pragma unroll
    for (int ts = 0; ts < 4; ++ts)
#pragma unroll
        for (int dt = 0; dt < 4; ++dt) O[ts][dt] = (f32x4){0.f, 0.f, 0.f, 0.f};
    float lr[4] = {0.f, 0.f, 0.f, 0.f};

#define CHUNK(cc) do {                                                       \
        const u16* Kl = &KVl[(cc) & 1][0];                                   \
        const u16* Vl = &KVl[(cc) & 1][4096];                                \
        bf16x8 kf[4][2];                                                     \
        _Pragma("unroll")                                                    \
        for (int st = 0; st < 4; ++st) {                                     \
            kf[st][0] = *(const bf16x8*)&Kl[st * 1024 + m * 64 + x0];        \
            kf[st][1] = *(const bf16x8*)&Kl[st * 1024 + m * 64 + x1];        \
        }                                                                    \
        float4 ng[4];                                                        \
        _Pragma("unroll")                                                    \
        for (int st = 0; st < 4; ++st)                                       \
            ng[st] = *(const float4*)&Ngl[((cc) << 6) + (st << 4) + (qd << 2)]; \
        _Pragma("unroll")                                                    \
        for (int ts = 0; ts < 4; ++ts) {                                     \
            f32x4 S[4];                                                      \
            _Pragma("unroll")                                                \
            for (int st = 0; st < 4; ++st) {                                 \
                f32x4 cc2 = (f32x4){0.f, 0.f, 0.f, 0.f};                     \
                cc2 = __builtin_amdgcn_mfma_f32_16x16x32_bf16(               \
                          kf[st][0], qf[ts][0], cc2, 0, 0, 0);               \
                cc2 = __builtin_amdgcn_mfma_f32_16x16x32_bf16(               \
                          kf[st][1], qf[ts][1], cc2, 0, 0, 0);               \
                S[st] = cc2;                                                 \
            }                                                                \
            float ls = 0.f;                                                  \
            _Pragma("unroll")                                                \
            for (int st = 0; st < 4; ++st) {                                 \
                const float p0 = fexp2(fmaf(S[st][0], SCL2, ng[st].x));      \
                const float p1 = fexp2(fmaf(S[st][1], SCL2, ng[st].y));      \
                const float p2 = fexp2(fmaf(S[st][2], SCL2, ng[st].z));      \
                const float p3 = fexp2(fmaf(S[st][3], SCL2, ng[st].w));      \
                ls += (p0 + p1) + (p2 + p3);                                 \
                *(uint2*)&Psh[waddr[st] + ts * 2048] =                       \
                    make_uint2(cvtpk(p0, p1), cvtpk(p2, p3));                \
            }                                                                \
            lr[ts] += ls;                                                    \
        }                                                                    \
        bf16x8 vf[4][2];                                                     \
        _Pragma("unroll")                                                    \
        for (int dt = 0; dt < 4; ++dt) {                                     \
            vf[dt][0] = *(const bf16x8*)&Vl[dt * 1024 + m * 64 + x0];        \
            vf[dt][1] = *(const bf16x8*)&Vl[dt * 1024 + m * 64 + x1];        \
        }                                                                    \
        __builtin_amdgcn_s_setprio(1);                                       \
        _Pragma("unroll")                                                    \
        for (int ts = 0; ts < 4; ++ts) {                                     \
            _Pragma("unroll")                                                \
            for (int ks = 0; ks < 2; ++ks) {                                 \
                const uint2 r0 = *(uint2*)&Psh[ra0[ks] + ts * 2048];         \
                const uint2 r1 = *(uint2*)&Psh[ra1[ks] + ts * 2048];         \
                union { uint4 u; bf16x8 v; } bu;                             \
                bu.u = make_uint4(r0.x, r0.y, r1.x, r1.y);                   \
                O[ts][0] = __builtin_amdgcn_mfma_f32_16x16x32_bf16(          \
                               vf[0][ks], bu.v, O[ts][0], 0, 0, 0);          \
                O[ts][1] = __builtin_amdgcn_mfma_f32_16x16x32_bf16(          \
                               vf[1][ks], bu.v, O[ts][1], 0, 0, 0);          \
                O[ts][2] = __builtin_amdgcn_mfma_f32_16x16x32_bf16(          \
                               vf[2][ks], bu.v, O[ts][2], 0, 0, 0);          \
                O[ts][3] = __builtin_amdgcn_mfma_f32_16x16x32_bf16(          \
                               vf[3][ks], bu.v, O[ts][3], 0, 0, 0);          \
            }                                                                \
        }                                                                    \
        __builtin_amdgcn_s_setprio(0);                                       \
    } while (0)

    // --- pipeline: stage(c+1) in flight across compute(c) ---
    STAGE(0, 0);
    gload_lds16((const u16*)(np + s_beg) + (size_t)tid * 8,
                ((u16*)Ngl) + tid * 8);
#pragma unroll 1
    for (int c = 0; c < (SCHUNK / 64) - 1; ++c) {
        STAGE(c + 1, (c + 1) & 1);
        asm volatile("s_waitcnt vmcnt(4)" ::: "memory");
        __builtin_amdgcn_s_barrier();
        __builtin_amdgcn_sched_barrier(0);
        CHUNK(c);
        __builtin_amdgcn_s_barrier();
        __builtin_amdgcn_sched_barrier(0);
    }
    asm volatile("s_waitcnt vmcnt(0)" ::: "memory");
    __builtin_amdgcn_s_barrier();
    __builtin_amdgcn_sched_barrier(0);
    CHUNK((SCHUNK / 64) - 1);

#undef STAGE
#undef CHUNK

#pragma unroll
    for (int ts = 0; ts < 4; ++ts) {
        float l = lr[ts];
        l += __shfl_xor(l, 16, 64);
        l += __shfl_xor(l, 32, 64);
        const int t = ti * 256 + 64 * w + 16 * ts + m;
        float* Ob = Opart + (((size_t)(si * 64 + bh)) * 512 + t) * 64;
#pragma unroll
        for (int dt = 0; dt < 4; ++dt)
            *(f32x4*)&Ob[16 * dt + 4 * qd] = O[ts][dt];
        if (qd == 0)
            lpart[((size_t)(si * 64 + bh)) * 512 + t] = l;
    }
}

// ---------------------------------------------------------------------------
// Combine split-S partials: ctx(B,T,512) bf16 = (sum O)/(sum l).
// ---------------------------------------------------------------------------
__global__ __launch_bounds__(256)
void attn_combine(const float* __restrict__ Opart, const float* __restrict__ lpart,
                  u16* __restrict__ ctx)
{
    const int gid = blockIdx.x * 256 + threadIdx.x;
    const int d4 = gid & 15, t = (gid >> 4) & 511, bh = gid >> 13;
    const int b = bh >> 3, h = bh & 7;
    float4 o = {0.f, 0.f, 0.f, 0.f}; float l = 0.f;
#pragma unroll
    for (int si = 0; si < SSPLIT; ++si) {
        const size_t base = ((size_t)(si * 64 + bh)) * 512 + t;
        l += lpart[base];
        const float4 v = *(const float4*)(Opart + base * 64 + d4 * 4);
        o.x += v.x; o.y += v.y; o.z += v.z; o.w += v.w;
    }
    const float r = 1.f / l;
    uint2 pk; pk.x = pkbf(o.x * r, o.y * r); pk.y = pkbf(o.z * r, o.w * r);
    *(uint2*)&ctx[((size_t)(b * 512 + t)) * 512 + h * 64 + d4 * 4] = pk;
}

// ---------------------------------------------------------------------------
extern "C" void kernel_launch(void* const* d_in, const int* in_sizes, int n_in,
                              void* d_out, int out_size, void* d_ws, size_t ws_size,
                              hipStream_t stream)
{
    const float* inputs  = (const float*)d_in[0];
    const float* targets = (const float*)d_in[1];
    const int*   mask    = (const int*)d_in[2];
    const float* Wq = (const float*)d_in[3];
    const float* bq = (const float*)d_in[4];
    const float* Wk = (const float*)d_in[5];
    const float* bk = (const float*)d_in[6];
    const float* Wv = (const float*)d_in[7];
    const float* bv = (const float*)d_in[8];
    const float* Wo = (const float*)d_in[9];
    const float* bo = (const float*)d_in[10];

    char* ws = (char*)d_ws;
    u16*   Xc    = (u16*)(ws);                            // 33,554,432 B
    u16*   Tc    = (u16*)(ws + 33554432);                 //  4,194,304
    u16*   Wc    = (u16*)(ws + 37748736);                 //  2,097,152
    float* negf  = (float*)(ws + 39845888);               //    131,072
    u16*   Qws   = (u16*)(ws + 39976960);                 //  4,194,304
    u16*   Kws   = (u16*)(ws + 44171264);                 // 33,554,432
    u16*   Vtws  = (u16*)(ws + 77725696);                 // 33,554,432
    u16*   Cws   = (u16*)(ws + 111280128);                //  4,194,304
    float* Opart = (float*)(ws + 115474432);              // 33,554,432
    float* lpart = (float*)(ws + 149028864);              //    524,288

    cvt_all<<<19488, 256, 0, stream>>>(inputs, targets, Wq, Wk, Wv, Wo, mask,
                                       Xc, Tc, Wc, negf);

    // Fused Q+K+V projections (one launch, 2176 blocks)
    proj_all<<<2176, 256, 0, stream>>>(Wc, Tc, Xc, bq, bk, bv,
                                       Qws, Kws, Vtws);

    attn_part<<<dim3(2, SSPLIT, 64), 256, 0, stream>>>(Qws, Kws, Vtws, negf,
                                                       Opart, lpart);
    attn_combine<<<2048, 256, 0, stream>>>(Opart, lpart, Cws);

    gemm_out<<<dim3(4, 32), 256, 0, stream>>>(Cws, Wc + 786432, bo,
                                              (float*)d_out);
}